// Round 6
// baseline (213.111 us; speedup 1.0000x reference)
//
#include <hip/hip_runtime.h>
#include <hip/hip_bf16.h>

#define DIM   512
#define NSEQ  1024
#define NB    8
#define NH    8
#define HD    64
#define NTOK  8192   // NB*NSEQ

typedef __attribute__((ext_vector_type(8))) short  short8;
typedef __attribute__((ext_vector_type(4))) short  short4v;
typedef __attribute__((ext_vector_type(4))) float  floatx4;
typedef __attribute__((ext_vector_type(4))) int    intx4;
typedef __attribute__((ext_vector_type(2))) int    intx2;
typedef __attribute__((ext_vector_type(8))) __bf16 bf16x8;

__device__ inline short f2bf(float x) {
    union { float f; unsigned u; } c; c.f = x;
    unsigned r = c.u + 0x7fffu + ((c.u >> 16) & 1u);
    return (short)(r >> 16);
}
__device__ inline float bf2f(short s) {
    union { unsigned u; float f; } c; c.u = ((unsigned)(unsigned short)s) << 16;
    return c.f;
}
__device__ inline floatx4 mfma16(short8 a, short8 b, floatx4 c) {
    return __builtin_amdgcn_mfma_f32_16x16x32_bf16(
        __builtin_bit_cast(bf16x8, a), __builtin_bit_cast(bf16x8, b), c, 0, 0, 0);
}
__device__ inline floatx4 mfma_pv(short4v a, short4v b, floatx4 c) {
#if __has_builtin(__builtin_amdgcn_mfma_f32_16x16x16bf16_1k)
    return __builtin_amdgcn_mfma_f32_16x16x16bf16_1k(a, b, c, 0, 0, 0);
#else
    asm("v_mfma_f32_16x16x16_bf16 %0, %1, %2, %0" : "+v"(c) : "v"(a), "v"(b));
    return c;
#endif
}
__device__ inline void gld_lds16(const void* g, void* l) {
    __builtin_amdgcn_global_load_lds(
        (__attribute__((address_space(1))) void*)(g),
        (__attribute__((address_space(3))) void*)(l), 16, 0, 0);
}

// ---------------- prep: cast Q,K -> bf16 (blocks 0..8191) + tiled W transpose ----------------
__global__ __launch_bounds__(256) void prep_kernel(
        const float* __restrict__ Q, const float* __restrict__ K,
        const float* __restrict__ Wq, const float* __restrict__ Wk,
        const float* __restrict__ Wv, const float* __restrict__ Wo,
        short* __restrict__ Qb, short* __restrict__ Kb,
        short* __restrict__ WqT, short* __restrict__ WkT,
        short* __restrict__ WvT, short* __restrict__ WoT) {
    const int tid = threadIdx.x;
    if (blockIdx.x < 8192) {
        const int idx = blockIdx.x * 256 + tid;     // quads of 4 floats
        const float* src; short* dst; int qi;
        if (idx < 1048576) { src = Q; dst = Qb; qi = idx; }
        else               { src = K; dst = Kb; qi = idx - 1048576; }
        const float4 v = *(const float4*)(src + (size_t)qi * 4);
        short4v o;
        o.x = f2bf(v.x); o.y = f2bf(v.y); o.z = f2bf(v.z); o.w = f2bf(v.w);
        *(short4v*)(dst + (size_t)qi * 4) = o;
        return;
    }
    // transpose: 64x64 tiles, 64 tiles per W, 4 W's -> 256 blocks
    __shared__ short Ts[64 * 65];
    const int b = blockIdx.x - 8192;
    const int wsel = b >> 6, tile = b & 63;
    const int tr = (tile >> 3) * 64;                // k base
    const int tc = (tile & 7) * 64;                 // n base
    const float* src = (wsel == 0) ? Wq : (wsel == 1) ? Wk : (wsel == 2) ? Wv : Wo;
    short* dst       = (wsel == 0) ? WqT : (wsel == 1) ? WkT : (wsel == 2) ? WvT : WoT;
#pragma unroll
    for (int i = 0; i < 16; i++) {
        const int idx = i * 256 + tid;              // over 64x64
        const int r = idx >> 6, c = idx & 63;       // coalesced read
        Ts[c * 65 + r] = f2bf(src[(size_t)(tr + r) * 512 + tc + c]);
    }
    __syncthreads();
#pragma unroll
    for (int i = 0; i < 16; i++) {
        const int idx = i * 256 + tid;
        const int n = idx >> 6, k = idx & 63;       // coalesced write
        dst[(size_t)(tc + n) * 512 + tr + k] = Ts[n * 65 + k];
    }
}

// ---------------- fused QKV projection GEMM ----------------
// grid (64, 12): x = m-block (XCD-affinity for A tiles), y: sel = y>>2
__global__ __launch_bounds__(256) void proj_kernel(
        const short* __restrict__ Qb, const short* __restrict__ Kb,
        const short* __restrict__ WqT, const short* __restrict__ WkT,
        const short* __restrict__ WvT,
        const float* __restrict__ bq, const float* __restrict__ bk,
        const float* __restrict__ bv,
        short* __restrict__ Qpb, short* __restrict__ Kpb,
        short* __restrict__ Vt) {
    __shared__ __attribute__((aligned(16))) short smem[8704]; // As(4096)+Bs(4096); Ts aliases
    short* As = smem;
    short* Bs = smem + 4096;
    const int tid = threadIdx.x;
    const int w = tid >> 6, ln = tid & 63;
    const int quad = ln >> 4, col = ln & 15;
    const int nb = blockIdx.y;
    const int sel = nb >> 2;
    const int n0 = (nb & 3) * 128;
    const int m0 = blockIdx.x * 128;
    const int wr = w >> 1, wc = w & 1;
    const short* A    = (sel == 0) ? Qb : Kb;
    const short* BT   = (sel == 0) ? WqT : (sel == 1) ? WkT : WvT;
    const float* bias = (sel == 0) ? bq : (sel == 1) ? bk : bv;

    floatx4 acc[4][4];
#pragma unroll
    for (int i = 0; i < 4; i++)
#pragma unroll
        for (int j = 0; j < 4; j++) acc[i][j] = (floatx4)0.0f;

    for (int k0 = 0; k0 < 512; k0 += 32) {
        __syncthreads();
#pragma unroll
        for (int i = 0; i < 2; i++) {
            const int chunk = i * 4 + w;
            const int flat = (chunk * 64 + ln) * 8;
            const int r = flat >> 5, c = flat & 31;
            gld_lds16(A  + (size_t)(m0 + r) * 512 + k0 + c, As + chunk * 512);
            gld_lds16(BT + (size_t)(n0 + r) * 512 + k0 + c, Bs + chunk * 512);
        }
        __syncthreads();
        short8 af[4], bfr[4];
#pragma unroll
        for (int i = 0; i < 4; i++)
            af[i] = *(const short8*)&As[(wr * 64 + i * 16 + col) * 32 + quad * 8];
#pragma unroll
        for (int j = 0; j < 4; j++)
            bfr[j] = *(const short8*)&Bs[(wc * 64 + j * 16 + col) * 32 + quad * 8];
#pragma unroll
        for (int i = 0; i < 4; i++)
#pragma unroll
            for (int j = 0; j < 4; j++)
                acc[i][j] = mfma16(af[i], bfr[j], acc[i][j]);
    }

    if (sel < 2) {
        short* C = (sel == 0) ? Qpb : Kpb;
#pragma unroll
        for (int j = 0; j < 4; j++) {
            const int cc = n0 + wc * 64 + j * 16 + col;
            const float bj = bias[cc];
#pragma unroll
            for (int i = 0; i < 4; i++)
#pragma unroll
                for (int r = 0; r < 4; r++) {
                    const int row = m0 + wr * 64 + i * 16 + quad * 4 + r;
                    C[(size_t)row * 512 + cc] = f2bf(acc[i][j][r] + bj);
                }
        }
    } else {
        // transposed epilogue: Vt[dv][tok], two 64-col halves through LDS
        short* Ts = smem;                            // 64 x 136
        const int dvl = tid >> 2;
        const int tch = (tid & 3) * 32;
#pragma unroll
        for (int hc = 0; hc < 2; hc++) {
            __syncthreads();
            if (wc == hc) {
#pragma unroll
                for (int j = 0; j < 4; j++) {
                    const float bj = bias[n0 + hc * 64 + j * 16 + col];
#pragma unroll
                    for (int i = 0; i < 4; i++)
#pragma unroll
                        for (int r = 0; r < 4; r++)
                            Ts[(j * 16 + col) * 136 + wr * 64 + i * 16 + quad * 4 + r] =
                                f2bf(acc[i][j][r] + bj);
                }
            }
            __syncthreads();
#pragma unroll
            for (int u = 0; u < 4; u++)
                *(intx4*)(Vt + (size_t)(n0 + hc * 64 + dvl) * NTOK + m0 + tch + u * 8) =
                    *(const intx4*)&Ts[dvl * 136 + tch + u * 8];
        }
    }
}

// ---------------- out-proj GEMM: 128x64 tile, fused relu, bf16 out ----------------
// grid (64, 8): x = m-block (XCD affinity), y = n-block
__global__ __launch_bounds__(256) void gemm_out(
        const short* __restrict__ A, const short* __restrict__ BT,
        const float* __restrict__ bias, short* __restrict__ C) {
    __shared__ __attribute__((aligned(16))) short As[128 * 32];
    __shared__ __attribute__((aligned(16))) short Bs[64 * 32];
    const int tid = threadIdx.x;
    const int w = tid >> 6, ln = tid & 63;
    const int quad = ln >> 4, col = ln & 15;
    const int m0 = blockIdx.x * 128;
    const int n0 = blockIdx.y * 64;
    const int wr = w >> 1, wc = w & 1;

    floatx4 acc[4][2];
#pragma unroll
    for (int i = 0; i < 4; i++)
#pragma unroll
        for (int j = 0; j < 2; j++) acc[i][j] = (floatx4)0.0f;

    for (int k0 = 0; k0 < 512; k0 += 32) {
        __syncthreads();
#pragma unroll
        for (int i = 0; i < 3; i++) {
            const int ch = i * 4 + w;                // 0..11 (8 A-chunks, 4 B-chunks)
            if (ch < 8) {
                const int flat = (ch * 64 + ln) * 8;
                gld_lds16(A + (size_t)(m0 + (flat >> 5)) * 512 + k0 + (flat & 31),
                          As + ch * 512);
            } else {
                const int flat = ((ch - 8) * 64 + ln) * 8;
                gld_lds16(BT + (size_t)(n0 + (flat >> 5)) * 512 + k0 + (flat & 31),
                          Bs + (ch - 8) * 512);
            }
        }
        __syncthreads();
        short8 af[4], bfr[2];
#pragma unroll
        for (int i = 0; i < 4; i++)
            af[i] = *(const short8*)&As[(wr * 64 + i * 16 + col) * 32 + quad * 8];
#pragma unroll
        for (int j = 0; j < 2; j++)
            bfr[j] = *(const short8*)&Bs[(wc * 32 + j * 16 + col) * 32 + quad * 8];
#pragma unroll
        for (int i = 0; i < 4; i++)
#pragma unroll
            for (int j = 0; j < 2; j++)
                acc[i][j] = mfma16(af[i], bfr[j], acc[i][j]);
    }

#pragma unroll
    for (int j = 0; j < 2; j++) {
        const int cc = n0 + wc * 32 + j * 16 + col;
        const float bj = bias[cc];
#pragma unroll
        for (int i = 0; i < 4; i++)
#pragma unroll
            for (int r = 0; r < 4; r++) {
                const int row = m0 + wr * 64 + i * 16 + quad * 4 + r;
                C[(size_t)row * 512 + cc] = f2bf(fmaxf(acc[i][j][r] + bj, 0.0f));
            }
    }
}

// ---------------- fused flash attention + residual ----------------
// 128 thr (2 waves), 32 q-rows/wave (2 strips): kf/vf LDS reads amortized 2x.
// XOR-swizzled 64-short rows (bank-uniform-minimal), double buffer, XCD pin.
__global__ __launch_bounds__(128) void attn_kernel(
        const short* __restrict__ Qp, const short* __restrict__ Kp,
        const short* __restrict__ Vt, short* __restrict__ Xo) {
    __shared__ __attribute__((aligned(16))) short Ks[2][64 * 64];
    __shared__ __attribute__((aligned(16))) short Vs[2][64 * 64];
    const int tid = threadIdx.x;
    const int w = tid >> 6, ln = tid & 63;
    const int quad = ln >> 4, col = ln & 15;
    const int gid = blockIdx.x;
    const int h = gid & 7;                  // XCD pin: one head per XCD
    const int rest = gid >> 3;              // 0..127
    const int b = rest >> 4;                // 0..7
    const int q0 = (rest & 15) * 64 + w * 32;
    const size_t baseQ = (size_t)b * NSEQ * DIM + (size_t)h * HD;
    const size_t baseV = (size_t)h * HD * NTOK + (size_t)b * NSEQ;
    const float sc = 1.44269504089f / 22.6274169979f;   // log2e / sqrt(512)

    // Q fragments (B-operand), 2 strips, pre-scaled once
    short8 qa[2][2];
#pragma unroll
    for (int u = 0; u < 2; u++)
#pragma unroll
        for (int s = 0; s < 2; s++) {
            short8 raw = *(const short8*)(Qp + baseQ +
                (size_t)(q0 + u * 16 + col) * DIM + s * 32 + quad * 8);
            short8 sq;
#pragma unroll
            for (int j = 0; j < 8; j++) sq[j] = f2bf(bf2f(raw[j]) * sc);
            qa[u][s] = sq;
        }

    floatx4 oacc[2][4];
#pragma unroll
    for (int u = 0; u < 2; u++)
#pragma unroll
        for (int dt = 0; dt < 4; dt++) oacc[u][dt] = (floatx4)0.0f;
    float lp[2] = {0.f, 0.f};

    // staging: 512 16B-chunks; r=idx>>3 (row), c=idx&7; swizzle cs = c^(r&7)
    intx4 kreg[4], vreg[4];
#pragma unroll
    for (int i = 0; i < 4; i++) {
        const int idx = i * 128 + tid;
        kreg[i] = *(const intx4*)(Kp + baseQ + (size_t)(idx >> 3) * DIM + (idx & 7) * 8);
        vreg[i] = *(const intx4*)(Vt + baseV + (size_t)(idx >> 3) * NTOK + (idx & 7) * 8);
    }
#pragma unroll
    for (int i = 0; i < 4; i++) {
        const int idx = i * 128 + tid;
        const int r = idx >> 3, c = idx & 7, cs = c ^ (r & 7);
        *(intx4*)&Ks[0][r * 64 + cs * 8] = kreg[i];
        *(intx4*)&Vs[0][r * 64 + cs * 8] = vreg[i];
    }
    __syncthreads();

    for (int t = 0; t < 16; t++) {
        const int cur = t & 1;
        if (t < 15) {
            const int kn = (t + 1) * 64;
#pragma unroll
            for (int i = 0; i < 4; i++) {
                const int idx = i * 128 + tid;
                kreg[i] = *(const intx4*)(Kp + baseQ + (size_t)(kn + (idx >> 3)) * DIM + (idx & 7) * 8);
                vreg[i] = *(const intx4*)(Vt + baseV + (size_t)(idx >> 3) * NTOK + kn + (idx & 7) * 8);
            }
        }
        const short* Kc = Ks[cur];
        const short* Vc = Vs[cur];
#pragma unroll
        for (int nt = 0; nt < 4; nt++) {
            floatx4 z0 = (floatx4)0.0f, z1 = (floatx4)0.0f;
#pragma unroll
            for (int s = 0; s < 2; s++) {
                const int cs = (s * 4 + quad) ^ (col & 7);
                const short8 kf = *(const short8*)&Kc[(nt * 16 + col) * 64 + cs * 8];
                z0 = mfma16(kf, qa[0][s], z0);      // S^T tiles, both strips
                z1 = mfma16(kf, qa[1][s], z1);
            }
            const float a0 = exp2f(z0[0]), a1 = exp2f(z0[1]);
            const float a2 = exp2f(z0[2]), a3 = exp2f(z0[3]);
            const float b0 = exp2f(z1[0]), b1 = exp2f(z1[1]);
            const float b2 = exp2f(z1[2]), b3 = exp2f(z1[3]);
            lp[0] += (a0 + a1) + (a2 + a3);
            lp[1] += (b0 + b1) + (b2 + b3);
            const unsigned lo0 = __builtin_amdgcn_perm(
                __builtin_bit_cast(unsigned, a1), __builtin_bit_cast(unsigned, a0), 0x07060302u);
            const unsigned hi0 = __builtin_amdgcn_perm(
                __builtin_bit_cast(unsigned, a3), __builtin_bit_cast(unsigned, a2), 0x07060302u);
            const unsigned lo1 = __builtin_amdgcn_perm(
                __builtin_bit_cast(unsigned, b1), __builtin_bit_cast(unsigned, b0), 0x07060302u);
            const unsigned hi1 = __builtin_amdgcn_perm(
                __builtin_bit_cast(unsigned, b3), __builtin_bit_cast(unsigned, b2), 0x07060302u);
            intx2 pd0; pd0.x = (int)lo0; pd0.y = (int)hi0;
            intx2 pd1; pd1.x = (int)lo1; pd1.y = (int)hi1;
            const short4v pf0 = __builtin_bit_cast(short4v, pd0);
            const short4v pf1 = __builtin_bit_cast(short4v, pd1);
#pragma unroll
            for (int dt = 0; dt < 4; dt++) {
                const int cs = (nt * 2 + (quad >> 1)) ^ (col & 7);
                const short4v vf = *(const short4v*)&Vc[(dt * 16 + col) * 64 + cs * 8 + (quad & 1) * 4];
                oacc[0][dt] = mfma_pv(pf0, vf, oacc[0][dt]);
                oacc[1][dt] = mfma_pv(pf1, vf, oacc[1][dt]);
            }
        }
        if (t < 15) {
            const int nxt = cur ^ 1;
#pragma unroll
            for (int i = 0; i < 4; i++) {
                const int idx = i * 128 + tid;
                const int r = idx >> 3, c = idx & 7, cs = c ^ (r & 7);
                *(intx4*)&Ks[nxt][r * 64 + cs * 8] = kreg[i];
                *(intx4*)&Vs[nxt][r * 64 + cs * 8] = vreg[i];
            }
        }
        __syncthreads();
    }

#pragma unroll
    for (int u = 0; u < 2; u++) {
        float l = lp[u];
        l += __shfl_xor(l, 16);
        l += __shfl_xor(l, 32);
        float linv[4];
#pragma unroll
        for (int r = 0; r < 4; r++) linv[r] = 1.0f / __shfl(l, quad * 4 + r);
#pragma unroll
        for (int dt = 0; dt < 4; dt++) {
#pragma unroll
            for (int r = 0; r < 4; r++) {
                const int q = q0 + u * 16 + quad * 4 + r;
                const size_t off = baseQ + (size_t)q * DIM + dt * 16 + col;
                Xo[off] = f2bf(oacc[u][dt][r] * linv[r] + bf2f(Qp[off]));
            }
        }
    }
}

// ---------------- LayerNorm (wave per row), bf16 in, bf16 out ----------------
__global__ __launch_bounds__(256) void ln_kernel(
        const short* __restrict__ X, const float* __restrict__ g,
        const float* __restrict__ be, short* __restrict__ Yb) {
    const int row = blockIdx.x * 4 + (threadIdx.x >> 6);
    const int ln = threadIdx.x & 63;
    union { intx4 v; short s[8]; } u;
    u.v = *(const intx4*)(X + (size_t)row * DIM + ln * 8);
    float x[8];
#pragma unroll
    for (int j = 0; j < 8; j++) x[j] = bf2f(u.s[j]);
    float s = 0.f, q = 0.f;
#pragma unroll
    for (int j = 0; j < 8; j++) { s += x[j]; q += x[j] * x[j]; }
#pragma unroll
    for (int off = 1; off < 64; off <<= 1) {
        s += __shfl_xor(s, off);
        q += __shfl_xor(q, off);
    }
    const float mean = s * (1.0f / DIM);
    const float var = q * (1.0f / DIM) - mean * mean;
    const float rstd = rsqrtf(var + 1e-5f);
    const int c0 = ln * 8;
    union { intx4 v; short s[8]; } o;
#pragma unroll
    for (int j = 0; j < 8; j++)
        o.s[j] = f2bf((x[j] - mean) * rstd * g[c0 + j] + be[c0 + j]);
    *(intx4*)(Yb + (size_t)row * DIM + c0) = o.v;
}

// ---------------- final: out = LN1(Xln0 + Yrelu), bf16 ins, fp32 out ----------------
__global__ __launch_bounds__(256) void final_kernel(
        const short* __restrict__ Xr, const short* __restrict__ Yr,
        const float* __restrict__ g, const float* __restrict__ be,
        float* __restrict__ out) {
    const int row = blockIdx.x * 4 + (threadIdx.x >> 6);
    const int ln = threadIdx.x & 63;
    const size_t rb = (size_t)row * DIM;
    const int c0 = ln * 8;
    union { intx4 v; short s[8]; } ux, uy;
    ux.v = *(const intx4*)(Xr + rb + c0);
    uy.v = *(const intx4*)(Yr + rb + c0);
    float x[8];
#pragma unroll
    for (int j = 0; j < 8; j++) x[j] = bf2f(ux.s[j]) + bf2f(uy.s[j]);
    float s = 0.f, q = 0.f;
#pragma unroll
    for (int j = 0; j < 8; j++) { s += x[j]; q += x[j] * x[j]; }
#pragma unroll
    for (int off = 1; off < 64; off <<= 1) {
        s += __shfl_xor(s, off);
        q += __shfl_xor(q, off);
    }
    const float mean = s * (1.0f / DIM);
    const float var = q * (1.0f / DIM) - mean * mean;
    const float rstd = rsqrtf(var + 1e-5f);
    float4 f0, f1;
    f0.x = (x[0] - mean) * rstd * g[c0 + 0] + be[c0 + 0];
    f0.y = (x[1] - mean) * rstd * g[c0 + 1] + be[c0 + 1];
    f0.z = (x[2] - mean) * rstd * g[c0 + 2] + be[c0 + 2];
    f0.w = (x[3] - mean) * rstd * g[c0 + 3] + be[c0 + 3];
    f1.x = (x[4] - mean) * rstd * g[c0 + 4] + be[c0 + 4];
    f1.y = (x[5] - mean) * rstd * g[c0 + 5] + be[c0 + 5];
    f1.z = (x[6] - mean) * rstd * g[c0 + 6] + be[c0 + 6];
    f1.w = (x[7] - mean) * rstd * g[c0 + 7] + be[c0 + 7];
    *(float4*)(out + rb + c0)     = f0;
    *(float4*)(out + rb + c0 + 4) = f1;
}

extern "C" void kernel_launch(void* const* d_in, const int* in_sizes, int n_in,
                              void* d_out, int out_size, void* d_ws, size_t ws_size,
                              hipStream_t stream) {
    const float* Q  = (const float*)d_in[0];
    const float* K  = (const float*)d_in[1];
    const float* Wq = (const float*)d_in[2];
    const float* bq = (const float*)d_in[3];
    const float* Wk = (const float*)d_in[4];
    const float* bk = (const float*)d_in[5];
    const float* Wv = (const float*)d_in[6];
    const float* bv = (const float*)d_in[7];
    const float* Wo = (const float*)d_in[8];
    const float* bo = (const float*)d_in[9];
    const float* g0 = (const float*)d_in[10];
    const float* b0 = (const float*)d_in[11];
    const float* g1 = (const float*)d_in[12];
    const float* b1 = (const float*)d_in[13];
    float* out = (float*)d_out;

    const size_t NE = (size_t)NTOK * DIM;
    char* p = (char*)d_ws;
    short* Qb   = (short*)p; p += NE * 2;
    short* Kb   = (short*)p; p += NE * 2;
    short* WqT  = (short*)p; p += 512 * 512 * 2;
    short* WkT  = (short*)p; p += 512 * 512 * 2;
    short* WvT  = (short*)p; p += 512 * 512 * 2;
    short* WoT  = (short*)p; p += 512 * 512 * 2;
    short* Qpb  = (short*)p; p += NE * 2;
    short* Kpb  = (short*)p; p += NE * 2;
    short* Vt   = (short*)p; p += NE * 2;   // [dv=512][tok=8192]
    short* Xat  = (short*)p; p += NE * 2;   // attn out + residual, bf16
    short* Xl0b = (short*)p; p += NE * 2;   // LN0 out, bf16
    short* Yob  = (short*)p; p += NE * 2;   // relu(out-proj), bf16

    prep_kernel<<<8448, 256, 0, stream>>>(Q, K, Wq, Wk, Wv, Wo,
                                          Qb, Kb, WqT, WkT, WvT, WoT);
    proj_kernel<<<dim3(64, 12), 256, 0, stream>>>(Qb, Kb, WqT, WkT, WvT,
                                                  bq, bk, bv, Qpb, Kpb, Vt);
    attn_kernel<<<1024, 128, 0, stream>>>(Qpb, Kpb, Vt, Xat);
    ln_kernel<<<2048, 256, 0, stream>>>(Xat, g0, b0, Xl0b);
    gemm_out<<<dim3(64, 8), 256, 0, stream>>>(Xl0b, WoT, bo, Yob);
    final_kernel<<<2048, 256, 0, stream>>>(Xl0b, Yob, g1, b1, out);
}

// Round 7
// 200.447 us; speedup vs baseline: 1.0632x; 1.0632x over previous
//
#include <hip/hip_runtime.h>
#include <hip/hip_bf16.h>

#define DIM   512
#define NSEQ  1024
#define NB    8
#define NH    8
#define HD    64
#define NTOK  8192   // NB*NSEQ

typedef __attribute__((ext_vector_type(8))) short  short8;
typedef __attribute__((ext_vector_type(4))) short  short4v;
typedef __attribute__((ext_vector_type(4))) float  floatx4;
typedef __attribute__((ext_vector_type(4))) int    intx4;
typedef __attribute__((ext_vector_type(2))) int    intx2;
typedef __attribute__((ext_vector_type(8))) __bf16 bf16x8;

__device__ inline short f2bf(float x) {
    union { float f; unsigned u; } c; c.f = x;
    unsigned r = c.u + 0x7fffu + ((c.u >> 16) & 1u);
    return (short)(r >> 16);
}
__device__ inline float bf2f(short s) {
    union { unsigned u; float f; } c; c.u = ((unsigned)(unsigned short)s) << 16;
    return c.f;
}
__device__ inline floatx4 mfma16(short8 a, short8 b, floatx4 c) {
    return __builtin_amdgcn_mfma_f32_16x16x32_bf16(
        __builtin_bit_cast(bf16x8, a), __builtin_bit_cast(bf16x8, b), c, 0, 0, 0);
}
__device__ inline floatx4 mfma_pv(short4v a, short4v b, floatx4 c) {
#if __has_builtin(__builtin_amdgcn_mfma_f32_16x16x16bf16_1k)
    return __builtin_amdgcn_mfma_f32_16x16x16bf16_1k(a, b, c, 0, 0, 0);
#else
    asm("v_mfma_f32_16x16x16_bf16 %0, %1, %2, %0" : "+v"(c) : "v"(a), "v"(b));
    return c;
#endif
}
__device__ inline void gld_lds16(const void* g, void* l) {
    __builtin_amdgcn_global_load_lds(
        (__attribute__((address_space(1))) void*)(g),
        (__attribute__((address_space(3))) void*)(l), 16, 0, 0);
}

// ---------------- prep: cast Q,K -> bf16 (blocks 0..8191) + tiled W transpose ----------------
__global__ __launch_bounds__(256) void prep_kernel(
        const float* __restrict__ Q, const float* __restrict__ K,
        const float* __restrict__ Wq, const float* __restrict__ Wk,
        const float* __restrict__ Wv, const float* __restrict__ Wo,
        short* __restrict__ Qb, short* __restrict__ Kb,
        short* __restrict__ WqT, short* __restrict__ WkT,
        short* __restrict__ WvT, short* __restrict__ WoT) {
    const int tid = threadIdx.x;
    if (blockIdx.x < 8192) {
        const int idx = blockIdx.x * 256 + tid;     // quads of 4 floats
        const float* src; short* dst; int qi;
        if (idx < 1048576) { src = Q; dst = Qb; qi = idx; }
        else               { src = K; dst = Kb; qi = idx - 1048576; }
        const float4 v = *(const float4*)(src + (size_t)qi * 4);
        short4v o;
        o.x = f2bf(v.x); o.y = f2bf(v.y); o.z = f2bf(v.z); o.w = f2bf(v.w);
        *(short4v*)(dst + (size_t)qi * 4) = o;
        return;
    }
    // transpose: 64x64 tiles, 64 tiles per W, 4 W's -> 256 blocks
    __shared__ short Ts[64 * 65];
    const int b = blockIdx.x - 8192;
    const int wsel = b >> 6, tile = b & 63;
    const int tr = (tile >> 3) * 64;                // k base
    const int tc = (tile & 7) * 64;                 // n base
    const float* src = (wsel == 0) ? Wq : (wsel == 1) ? Wk : (wsel == 2) ? Wv : Wo;
    short* dst       = (wsel == 0) ? WqT : (wsel == 1) ? WkT : (wsel == 2) ? WvT : WoT;
#pragma unroll
    for (int i = 0; i < 16; i++) {
        const int idx = i * 256 + tid;              // over 64x64
        const int r = idx >> 6, c = idx & 63;       // coalesced read
        Ts[c * 65 + r] = f2bf(src[(size_t)(tr + r) * 512 + tc + c]);
    }
    __syncthreads();
#pragma unroll
    for (int i = 0; i < 16; i++) {
        const int idx = i * 256 + tid;
        const int n = idx >> 6, k = idx & 63;       // coalesced write
        dst[(size_t)(tc + n) * 512 + tr + k] = Ts[n * 65 + k];
    }
}

// ---------------- fused QKV projection GEMM ----------------
// grid (64, 12): x = m-block (XCD-affinity for A tiles), y: sel = y>>2
__global__ __launch_bounds__(256) void proj_kernel(
        const short* __restrict__ Qb, const short* __restrict__ Kb,
        const short* __restrict__ WqT, const short* __restrict__ WkT,
        const short* __restrict__ WvT,
        const float* __restrict__ bq, const float* __restrict__ bk,
        const float* __restrict__ bv,
        short* __restrict__ Qpb, short* __restrict__ Kpb,
        short* __restrict__ Vt) {
    __shared__ __attribute__((aligned(16))) short smem[8704]; // As(4096)+Bs(4096); Ts aliases
    short* As = smem;
    short* Bs = smem + 4096;
    const int tid = threadIdx.x;
    const int w = tid >> 6, ln = tid & 63;
    const int quad = ln >> 4, col = ln & 15;
    const int nb = blockIdx.y;
    const int sel = nb >> 2;
    const int n0 = (nb & 3) * 128;
    const int m0 = blockIdx.x * 128;
    const int wr = w >> 1, wc = w & 1;
    const short* A    = (sel == 0) ? Qb : Kb;
    const short* BT   = (sel == 0) ? WqT : (sel == 1) ? WkT : WvT;
    const float* bias = (sel == 0) ? bq : (sel == 1) ? bk : bv;

    floatx4 acc[4][4];
#pragma unroll
    for (int i = 0; i < 4; i++)
#pragma unroll
        for (int j = 0; j < 4; j++) acc[i][j] = (floatx4)0.0f;

    for (int k0 = 0; k0 < 512; k0 += 32) {
        __syncthreads();
#pragma unroll
        for (int i = 0; i < 2; i++) {
            const int chunk = i * 4 + w;
            const int flat = (chunk * 64 + ln) * 8;
            const int r = flat >> 5, c = flat & 31;
            gld_lds16(A  + (size_t)(m0 + r) * 512 + k0 + c, As + chunk * 512);
            gld_lds16(BT + (size_t)(n0 + r) * 512 + k0 + c, Bs + chunk * 512);
        }
        __syncthreads();
        short8 af[4], bfr[4];
#pragma unroll
        for (int i = 0; i < 4; i++)
            af[i] = *(const short8*)&As[(wr * 64 + i * 16 + col) * 32 + quad * 8];
#pragma unroll
        for (int j = 0; j < 4; j++)
            bfr[j] = *(const short8*)&Bs[(wc * 64 + j * 16 + col) * 32 + quad * 8];
#pragma unroll
        for (int i = 0; i < 4; i++)
#pragma unroll
            for (int j = 0; j < 4; j++)
                acc[i][j] = mfma16(af[i], bfr[j], acc[i][j]);
    }

    if (sel < 2) {
        short* C = (sel == 0) ? Qpb : Kpb;
#pragma unroll
        for (int j = 0; j < 4; j++) {
            const int cc = n0 + wc * 64 + j * 16 + col;
            const float bj = bias[cc];
#pragma unroll
            for (int i = 0; i < 4; i++)
#pragma unroll
                for (int r = 0; r < 4; r++) {
                    const int row = m0 + wr * 64 + i * 16 + quad * 4 + r;
                    C[(size_t)row * 512 + cc] = f2bf(acc[i][j][r] + bj);
                }
        }
    } else {
        // transposed epilogue: Vt[dv][tok], two 64-col halves through LDS
        short* Ts = smem;                            // 64 x 136
        const int dvl = tid >> 2;
        const int tch = (tid & 3) * 32;
#pragma unroll
        for (int hc = 0; hc < 2; hc++) {
            __syncthreads();
            if (wc == hc) {
#pragma unroll
                for (int j = 0; j < 4; j++) {
                    const float bj = bias[n0 + hc * 64 + j * 16 + col];
#pragma unroll
                    for (int i = 0; i < 4; i++)
#pragma unroll
                        for (int r = 0; r < 4; r++)
                            Ts[(j * 16 + col) * 136 + wr * 64 + i * 16 + quad * 4 + r] =
                                f2bf(acc[i][j][r] + bj);
                }
            }
            __syncthreads();
#pragma unroll
            for (int u = 0; u < 4; u++)
                *(intx4*)(Vt + (size_t)(n0 + hc * 64 + dvl) * NTOK + m0 + tch + u * 8) =
                    *(const intx4*)&Ts[dvl * 136 + tch + u * 8];
        }
    }
}

// ---------------- out-proj GEMM: 128x64 tile, fused relu, bf16 out ----------------
// grid (64, 8): x = m-block (XCD affinity), y = n-block
__global__ __launch_bounds__(256) void gemm_out(
        const short* __restrict__ A, const short* __restrict__ BT,
        const float* __restrict__ bias, short* __restrict__ C) {
    __shared__ __attribute__((aligned(16))) short As[128 * 32];
    __shared__ __attribute__((aligned(16))) short Bs[64 * 32];
    const int tid = threadIdx.x;
    const int w = tid >> 6, ln = tid & 63;
    const int quad = ln >> 4, col = ln & 15;
    const int m0 = blockIdx.x * 128;
    const int n0 = blockIdx.y * 64;
    const int wr = w >> 1, wc = w & 1;

    floatx4 acc[4][2];
#pragma unroll
    for (int i = 0; i < 4; i++)
#pragma unroll
        for (int j = 0; j < 2; j++) acc[i][j] = (floatx4)0.0f;

    for (int k0 = 0; k0 < 512; k0 += 32) {
        __syncthreads();
#pragma unroll
        for (int i = 0; i < 3; i++) {
            const int ch = i * 4 + w;                // 0..11 (8 A-chunks, 4 B-chunks)
            if (ch < 8) {
                const int flat = (ch * 64 + ln) * 8;
                gld_lds16(A + (size_t)(m0 + (flat >> 5)) * 512 + k0 + (flat & 31),
                          As + ch * 512);
            } else {
                const int flat = ((ch - 8) * 64 + ln) * 8;
                gld_lds16(BT + (size_t)(n0 + (flat >> 5)) * 512 + k0 + (flat & 31),
                          Bs + (ch - 8) * 512);
            }
        }
        __syncthreads();
        short8 af[4], bfr[2];
#pragma unroll
        for (int i = 0; i < 4; i++)
            af[i] = *(const short8*)&As[(wr * 64 + i * 16 + col) * 32 + quad * 8];
#pragma unroll
        for (int j = 0; j < 2; j++)
            bfr[j] = *(const short8*)&Bs[(wc * 32 + j * 16 + col) * 32 + quad * 8];
#pragma unroll
        for (int i = 0; i < 4; i++)
#pragma unroll
            for (int j = 0; j < 2; j++)
                acc[i][j] = mfma16(af[i], bfr[j], acc[i][j]);
    }

#pragma unroll
    for (int j = 0; j < 2; j++) {
        const int cc = n0 + wc * 32 + j * 16 + col;
        const float bj = bias[cc];
#pragma unroll
        for (int i = 0; i < 4; i++)
#pragma unroll
            for (int r = 0; r < 4; r++) {
                const int row = m0 + wr * 64 + i * 16 + quad * 4 + r;
                C[(size_t)row * 512 + cc] = f2bf(fmaxf(acc[i][j][r] + bj, 0.0f));
            }
    }
}

// ---------------- fused flash attention + residual ----------------
// 256 thr / 16 q-rows per wave (R5 occupancy point), XCD pin (h = gid&7),
// KT=64 double buffer filled by global_load_lds DMA with SOURCE-side XOR
// swizzle (LDS slot ell holds global chunk (ell&7)^(r&7) of row r=ell>>3):
// no ds_writes at all; reads are <=2-way per quarter-wave.
__global__ __launch_bounds__(256) void attn_kernel(
        const short* __restrict__ Qp, const short* __restrict__ Kp,
        const short* __restrict__ Vt, short* __restrict__ Xo) {
    __shared__ __attribute__((aligned(16))) short Ks[2][64 * 64];
    __shared__ __attribute__((aligned(16))) short Vs[2][64 * 64];
    const int tid = threadIdx.x;
    const int w = tid >> 6, ln = tid & 63;
    const int quad = ln >> 4, col = ln & 15;
    const int gid = blockIdx.x;
    const int h = gid & 7;                  // XCD pin: one head per XCD
    const int rest = gid >> 3;              // 0..127
    const int b = rest >> 4;                // 0..7
    const int q0 = (rest & 15) * 64 + w * 16;
    const size_t baseQ = (size_t)b * NSEQ * DIM + (size_t)h * HD;
    const size_t baseV = (size_t)h * HD * NTOK + (size_t)b * NSEQ;
    const float sc = 1.44269504089f / 22.6274169979f;   // log2e / sqrt(512)

    // DMA source addresses for this thread (slot = i*256 + tid)
    // slot -> r = slot>>3, swizzled source chunk c = (slot&7) ^ (r&7)
    const int slot0 = tid, slot1 = 256 + tid;
    const int r0 = slot0 >> 3, c0 = (slot0 & 7) ^ (r0 & 7);
    const int r1 = slot1 >> 3, c1 = (slot1 & 7) ^ (r1 & 7);
    const short* kp0 = Kp + baseQ + (size_t)r0 * DIM + c0 * 8;
    const short* kp1 = Kp + baseQ + (size_t)r1 * DIM + c1 * 8;
    const short* vp0 = Vt + baseV + (size_t)r0 * NTOK + c0 * 8;
    const short* vp1 = Vt + baseV + (size_t)r1 * NTOK + c1 * 8;
    // wave-uniform LDS dest bases (HW adds lane*16)
    const int ldsl0 = (w * 64) * 8;          // slot block i=0
    const int ldsl1 = (256 + w * 64) * 8;    // slot block i=1

    // Q fragments (B-operand), pre-scaled once
    short8 qa[2];
#pragma unroll
    for (int s = 0; s < 2; s++) {
        short8 raw = *(const short8*)(Qp + baseQ + (size_t)(q0 + col) * DIM + s * 32 + quad * 8);
        short8 sq;
#pragma unroll
        for (int j = 0; j < 8; j++) sq[j] = f2bf(bf2f(raw[j]) * sc);
        qa[s] = sq;
    }

    floatx4 oacc[4];
#pragma unroll
    for (int dt = 0; dt < 4; dt++) oacc[dt] = (floatx4)0.0f;
    float lp = 0.0f;

    // prologue: DMA tile 0 into buffer 0
    gld_lds16(kp0, &Ks[0][ldsl0]);
    gld_lds16(kp1, &Ks[0][ldsl1]);
    gld_lds16(vp0, &Vs[0][ldsl0]);
    gld_lds16(vp1, &Vs[0][ldsl1]);
    __syncthreads();

    for (int t = 0; t < 16; t++) {
        const int cur = t & 1;
        if (t < 15) {
            const int kn = (t + 1) * 64;     // K advances by rows, V by cols
            const int nxt = cur ^ 1;
            gld_lds16(kp0 + (size_t)kn * DIM, &Ks[nxt][ldsl0]);
            gld_lds16(kp1 + (size_t)kn * DIM, &Ks[nxt][ldsl1]);
            gld_lds16(vp0 + kn, &Vs[nxt][ldsl0]);
            gld_lds16(vp1 + kn, &Vs[nxt][ldsl1]);
        }
        const short* Kc = Ks[cur];
        const short* Vc = Vs[cur];
#pragma unroll
        for (int nt = 0; nt < 4; nt++) {
            floatx4 z = (floatx4)0.0f;
#pragma unroll
            for (int s = 0; s < 2; s++) {
                const int cs = (s * 4 + quad) ^ (col & 7);
                const short8 kf = *(const short8*)&Kc[(nt * 16 + col) * 64 + cs * 8];
                z = mfma16(kf, qa[s], z);           // S^T tile
            }
            const float p0 = exp2f(z[0]), p1 = exp2f(z[1]);
            const float p2 = exp2f(z[2]), p3 = exp2f(z[3]);
            lp += (p0 + p1) + (p2 + p3);
            const unsigned lo = __builtin_amdgcn_perm(
                __builtin_bit_cast(unsigned, p1), __builtin_bit_cast(unsigned, p0), 0x07060302u);
            const unsigned hi = __builtin_amdgcn_perm(
                __builtin_bit_cast(unsigned, p3), __builtin_bit_cast(unsigned, p2), 0x07060302u);
            intx2 pd; pd.x = (int)lo; pd.y = (int)hi;
            const short4v pf = __builtin_bit_cast(short4v, pd);
#pragma unroll
            for (int dt = 0; dt < 4; dt++) {
                const int cs = (nt * 2 + (quad >> 1)) ^ (col & 7);
                const short4v vf = *(const short4v*)&Vc[(dt * 16 + col) * 64 + cs * 8 + (quad & 1) * 4];
                oacc[dt] = mfma_pv(pf, vf, oacc[dt]);
            }
        }
        __syncthreads();
    }

    lp += __shfl_xor(lp, 16);
    lp += __shfl_xor(lp, 32);
    float linv[4];
#pragma unroll
    for (int r = 0; r < 4; r++) linv[r] = 1.0f / __shfl(lp, quad * 4 + r);

#pragma unroll
    for (int dt = 0; dt < 4; dt++) {
#pragma unroll
        for (int r = 0; r < 4; r++) {
            const int q = q0 + quad * 4 + r;
            const size_t off = baseQ + (size_t)q * DIM + dt * 16 + col;
            Xo[off] = f2bf(oacc[dt][r] * linv[r] + bf2f(Qp[off]));
        }
    }
}

// ---------------- LayerNorm (wave per row), bf16 in, bf16 out ----------------
__global__ __launch_bounds__(256) void ln_kernel(
        const short* __restrict__ X, const float* __restrict__ g,
        const float* __restrict__ be, short* __restrict__ Yb) {
    const int row = blockIdx.x * 4 + (threadIdx.x >> 6);
    const int ln = threadIdx.x & 63;
    union { intx4 v; short s[8]; } u;
    u.v = *(const intx4*)(X + (size_t)row * DIM + ln * 8);
    float x[8];
#pragma unroll
    for (int j = 0; j < 8; j++) x[j] = bf2f(u.s[j]);
    float s = 0.f, q = 0.f;
#pragma unroll
    for (int j = 0; j < 8; j++) { s += x[j]; q += x[j] * x[j]; }
#pragma unroll
    for (int off = 1; off < 64; off <<= 1) {
        s += __shfl_xor(s, off);
        q += __shfl_xor(q, off);
    }
    const float mean = s * (1.0f / DIM);
    const float var = q * (1.0f / DIM) - mean * mean;
    const float rstd = rsqrtf(var + 1e-5f);
    const int c0 = ln * 8;
    union { intx4 v; short s[8]; } o;
#pragma unroll
    for (int j = 0; j < 8; j++)
        o.s[j] = f2bf((x[j] - mean) * rstd * g[c0 + j] + be[c0 + j]);
    *(intx4*)(Yb + (size_t)row * DIM + c0) = o.v;
}

// ---------------- final: out = LN1(Xln0 + Yrelu), bf16 ins, fp32 out ----------------
__global__ __launch_bounds__(256) void final_kernel(
        const short* __restrict__ Xr, const short* __restrict__ Yr,
        const float* __restrict__ g, const float* __restrict__ be,
        float* __restrict__ out) {
    const int row = blockIdx.x * 4 + (threadIdx.x >> 6);
    const int ln = threadIdx.x & 63;
    const size_t rb = (size_t)row * DIM;
    const int c0 = ln * 8;
    union { intx4 v; short s[8]; } ux, uy;
    ux.v = *(const intx4*)(Xr + rb + c0);
    uy.v = *(const intx4*)(Yr + rb + c0);
    float x[8];
#pragma unroll
    for (int j = 0; j < 8; j++) x[j] = bf2f(ux.s[j]) + bf2f(uy.s[j]);
    float s = 0.f, q = 0.f;
#pragma unroll
    for (int j = 0; j < 8; j++) { s += x[j]; q += x[j] * x[j]; }
#pragma unroll
    for (int off = 1; off < 64; off <<= 1) {
        s += __shfl_xor(s, off);
        q += __shfl_xor(q, off);
    }
    const float mean = s * (1.0f / DIM);
    const float var = q * (1.0f / DIM) - mean * mean;
    const float rstd = rsqrtf(var + 1e-5f);
    float4 f0, f1;
    f0.x = (x[0] - mean) * rstd * g[c0 + 0] + be[c0 + 0];
    f0.y = (x[1] - mean) * rstd * g[c0 + 1] + be[c0 + 1];
    f0.z = (x[2] - mean) * rstd * g[c0 + 2] + be[c0 + 2];
    f0.w = (x[3] - mean) * rstd * g[c0 + 3] + be[c0 + 3];
    f1.x = (x[4] - mean) * rstd * g[c0 + 4] + be[c0 + 4];
    f1.y = (x[5] - mean) * rstd * g[c0 + 5] + be[c0 + 5];
    f1.z = (x[6] - mean) * rstd * g[c0 + 6] + be[c0 + 6];
    f1.w = (x[7] - mean) * rstd * g[c0 + 7] + be[c0 + 7];
    *(float4*)(out + rb + c0)     = f0;
    *(float4*)(out + rb + c0 + 4) = f1;
}

extern "C" void kernel_launch(void* const* d_in, const int* in_sizes, int n_in,
                              void* d_out, int out_size, void* d_ws, size_t ws_size,
                              hipStream_t stream) {
    const float* Q  = (const float*)d_in[0];
    const float* K  = (const float*)d_in[1];
    const float* Wq = (const float*)d_in[2];
    const float* bq = (const float*)d_in[3];
    const float* Wk = (const float*)d_in[4];
    const float* bk = (const float*)d_in[5];
    const float* Wv = (const float*)d_in[6];
    const float* bv = (const float*)d_in[7];
    const float* Wo = (const float*)d_in[8];
    const float* bo = (const float*)d_in[9];
    const float* g0 = (const float*)d_in[10];
    const float* b0 = (const float*)d_in[11];
    const float* g1 = (const float*)d_in[12];
    const float* b1 = (const float*)d_in[13];
    float* out = (float*)d_out;

    const size_t NE = (size_t)NTOK * DIM;
    char* p = (char*)d_ws;
    short* Qb   = (short*)p; p += NE * 2;
    short* Kb   = (short*)p; p += NE * 2;
    short* WqT  = (short*)p; p += 512 * 512 * 2;
    short* WkT  = (short*)p; p += 512 * 512 * 2;
    short* WvT  = (short*)p; p += 512 * 512 * 2;
    short* WoT  = (short*)p; p += 512 * 512 * 2;
    short* Qpb  = (short*)p; p += NE * 2;
    short* Kpb  = (short*)p; p += NE * 2;
    short* Vt   = (short*)p; p += NE * 2;   // [dv=512][tok=8192]
    short* Xat  = (short*)p; p += NE * 2;   // attn out + residual, bf16
    short* Xl0b = (short*)p; p += NE * 2;   // LN0 out, bf16
    short* Yob  = (short*)p; p += NE * 2;   // relu(out-proj), bf16

    prep_kernel<<<8448, 256, 0, stream>>>(Q, K, Wq, Wk, Wv, Wo,
                                          Qb, Kb, WqT, WkT, WvT, WoT);
    proj_kernel<<<dim3(64, 12), 256, 0, stream>>>(Qb, Kb, WqT, WkT, WvT,
                                                  bq, bk, bv, Qpb, Kpb, Vt);
    attn_kernel<<<1024, 256, 0, stream>>>(Qpb, Kpb, Vt, Xat);
    ln_kernel<<<2048, 256, 0, stream>>>(Xat, g0, b0, Xl0b);
    gemm_out<<<dim3(64, 8), 256, 0, stream>>>(Xl0b, WoT, bo, Yob);
    final_kernel<<<2048, 256, 0, stream>>>(Xl0b, Yob, g1, b1, out);
}

// Round 8
// 196.211 us; speedup vs baseline: 1.0861x; 1.0216x over previous
//
#include <hip/hip_runtime.h>
#include <hip/hip_bf16.h>

#define DIM   512
#define NSEQ  1024
#define NB    8
#define NH    8
#define HD    64
#define NTOK  8192   // NB*NSEQ

typedef __attribute__((ext_vector_type(8))) short  short8;
typedef __attribute__((ext_vector_type(4))) short  short4v;
typedef __attribute__((ext_vector_type(4))) float  floatx4;
typedef __attribute__((ext_vector_type(4))) int    intx4;
typedef __attribute__((ext_vector_type(2))) int    intx2;
typedef __attribute__((ext_vector_type(8))) __bf16 bf16x8;

__device__ inline short f2bf(float x) {
    union { float f; unsigned u; } c; c.f = x;
    unsigned r = c.u + 0x7fffu + ((c.u >> 16) & 1u);
    return (short)(r >> 16);
}
__device__ inline float bf2f(short s) {
    union { unsigned u; float f; } c; c.u = ((unsigned)(unsigned short)s) << 16;
    return c.f;
}
__device__ inline floatx4 mfma16(short8 a, short8 b, floatx4 c) {
    return __builtin_amdgcn_mfma_f32_16x16x32_bf16(
        __builtin_bit_cast(bf16x8, a), __builtin_bit_cast(bf16x8, b), c, 0, 0, 0);
}
__device__ inline floatx4 mfma_pv(short4v a, short4v b, floatx4 c) {
#if __has_builtin(__builtin_amdgcn_mfma_f32_16x16x16bf16_1k)
    return __builtin_amdgcn_mfma_f32_16x16x16bf16_1k(a, b, c, 0, 0, 0);
#else
    asm("v_mfma_f32_16x16x16_bf16 %0, %1, %2, %0" : "+v"(c) : "v"(a), "v"(b));
    return c;
#endif
}
__device__ inline void gld_lds16(const void* g, void* l) {
    __builtin_amdgcn_global_load_lds(
        (__attribute__((address_space(1))) void*)(g),
        (__attribute__((address_space(3))) void*)(l), 16, 0, 0);
}

// ---------------- prep: cast Q,K -> bf16 (blocks 0..8191) + tiled W transpose ----------------
__global__ __launch_bounds__(256) void prep_kernel(
        const float* __restrict__ Q, const float* __restrict__ K,
        const float* __restrict__ Wq, const float* __restrict__ Wk,
        const float* __restrict__ Wv, const float* __restrict__ Wo,
        short* __restrict__ Qb, short* __restrict__ Kb,
        short* __restrict__ WqT, short* __restrict__ WkT,
        short* __restrict__ WvT, short* __restrict__ WoT) {
    const int tid = threadIdx.x;
    if (blockIdx.x < 8192) {
        const int idx = blockIdx.x * 256 + tid;     // quads of 4 floats
        const float* src; short* dst; int qi;
        if (idx < 1048576) { src = Q; dst = Qb; qi = idx; }
        else               { src = K; dst = Kb; qi = idx - 1048576; }
        const float4 v = *(const float4*)(src + (size_t)qi * 4);
        short4v o;
        o.x = f2bf(v.x); o.y = f2bf(v.y); o.z = f2bf(v.z); o.w = f2bf(v.w);
        *(short4v*)(dst + (size_t)qi * 4) = o;
        return;
    }
    // transpose: 64x64 tiles, 64 tiles per W, 4 W's -> 256 blocks
    __shared__ short Ts[64 * 65];
    const int b = blockIdx.x - 8192;
    const int wsel = b >> 6, tile = b & 63;
    const int tr = (tile >> 3) * 64;                // k base
    const int tc = (tile & 7) * 64;                 // n base
    const float* src = (wsel == 0) ? Wq : (wsel == 1) ? Wk : (wsel == 2) ? Wv : Wo;
    short* dst       = (wsel == 0) ? WqT : (wsel == 1) ? WkT : (wsel == 2) ? WvT : WoT;
#pragma unroll
    for (int i = 0; i < 16; i++) {
        const int idx = i * 256 + tid;              // over 64x64
        const int r = idx >> 6, c = idx & 63;       // coalesced read
        Ts[c * 65 + r] = f2bf(src[(size_t)(tr + r) * 512 + tc + c]);
    }
    __syncthreads();
#pragma unroll
    for (int i = 0; i < 16; i++) {
        const int idx = i * 256 + tid;
        const int n = idx >> 6, k = idx & 63;       // coalesced write
        dst[(size_t)(tc + n) * 512 + tr + k] = Ts[n * 65 + k];
    }
}

// ---------------- fused QKV projection GEMM, BK=64, swizzled DMA staging ----------------
// grid (64, 12): x = m-block (XCD-affinity for A tiles), y: sel = y>>2
// LDS image is packed 128x64 bf16 with chunk swizzle cs = c ^ (r&7) applied on
// the SOURCE address; fragment reads then hit every bank exactly 2x (free).
__global__ __launch_bounds__(256) void proj_kernel(
        const short* __restrict__ Qb, const short* __restrict__ Kb,
        const short* __restrict__ WqT, const short* __restrict__ WkT,
        const short* __restrict__ WvT,
        const float* __restrict__ bq, const float* __restrict__ bk,
        const float* __restrict__ bv,
        short* __restrict__ Qpb, short* __restrict__ Kpb,
        short* __restrict__ Vt) {
    __shared__ __attribute__((aligned(16))) short smem[16384]; // As 8192 + Bs 8192; Ts aliases
    short* As = smem;
    short* Bs = smem + 8192;
    const int tid = threadIdx.x;
    const int w = tid >> 6, ln = tid & 63;
    const int quad = ln >> 4, col = ln & 15;
    const int nb = blockIdx.y;
    const int sel = nb >> 2;
    const int n0 = (nb & 3) * 128;
    const int m0 = blockIdx.x * 128;
    const int wr = w >> 1, wc = w & 1;
    const short* A    = (sel == 0) ? Qb : Kb;
    const short* BT   = (sel == 0) ? WqT : (sel == 1) ? WkT : WvT;
    const float* bias = (sel == 0) ? bq : (sel == 1) ? bk : bv;

    floatx4 acc[4][4];
#pragma unroll
    for (int i = 0; i < 4; i++)
#pragma unroll
        for (int j = 0; j < 4; j++) acc[i][j] = (floatx4)0.0f;

    for (int k0 = 0; k0 < 512; k0 += 64) {
        __syncthreads();
#pragma unroll
        for (int i = 0; i < 4; i++) {
            const int slot = i * 256 + tid;          // 1024 chunks of 16B
            const int r = slot >> 3;                 // tile row 0..127
            const int c = (slot & 7) ^ (r & 7);      // swizzled source chunk
            gld_lds16(A  + (size_t)(m0 + r) * 512 + k0 + c * 8, As + slot * 8);
            gld_lds16(BT + (size_t)(n0 + r) * 512 + k0 + c * 8, Bs + slot * 8);
        }
        __syncthreads();
#pragma unroll
        for (int s = 0; s < 2; s++) {
            short8 af[4], bfr[4];
#pragma unroll
            for (int i = 0; i < 4; i++) {
                const int row = wr * 64 + i * 16 + col;
                const int cs = (s * 4 + quad) ^ (col & 7);
                af[i] = *(const short8*)&As[row * 64 + cs * 8];
            }
#pragma unroll
            for (int j = 0; j < 4; j++) {
                const int row = wc * 64 + j * 16 + col;
                const int cs = (s * 4 + quad) ^ (col & 7);
                bfr[j] = *(const short8*)&Bs[row * 64 + cs * 8];
            }
#pragma unroll
            for (int i = 0; i < 4; i++)
#pragma unroll
                for (int j = 0; j < 4; j++)
                    acc[i][j] = mfma16(af[i], bfr[j], acc[i][j]);
        }
    }

    if (sel < 2) {
        short* C = (sel == 0) ? Qpb : Kpb;
#pragma unroll
        for (int j = 0; j < 4; j++) {
            const int cc = n0 + wc * 64 + j * 16 + col;
            const float bj = bias[cc];
#pragma unroll
            for (int i = 0; i < 4; i++)
#pragma unroll
                for (int r = 0; r < 4; r++) {
                    const int row = m0 + wr * 64 + i * 16 + quad * 4 + r;
                    C[(size_t)row * 512 + cc] = f2bf(acc[i][j][r] + bj);
                }
        }
    } else {
        // transposed epilogue: Vt[dv][tok], two 64-col halves through LDS
        short* Ts = smem;                            // 64 x 136 = 8704 <= 16384
        const int dvl = tid >> 2;
        const int tch = (tid & 3) * 32;
#pragma unroll
        for (int hc = 0; hc < 2; hc++) {
            __syncthreads();
            if (wc == hc) {
#pragma unroll
                for (int j = 0; j < 4; j++) {
                    const float bj = bias[n0 + hc * 64 + j * 16 + col];
#pragma unroll
                    for (int i = 0; i < 4; i++)
#pragma unroll
                        for (int r = 0; r < 4; r++)
                            Ts[(j * 16 + col) * 136 + wr * 64 + i * 16 + quad * 4 + r] =
                                f2bf(acc[i][j][r] + bj);
                }
            }
            __syncthreads();
#pragma unroll
            for (int u = 0; u < 4; u++)
                *(intx4*)(Vt + (size_t)(n0 + hc * 64 + dvl) * NTOK + m0 + tch + u * 8) =
                    *(const intx4*)&Ts[dvl * 136 + tch + u * 8];
        }
    }
}

// ---------------- out-proj GEMM: 128x64 tile, BK=64, swizzled DMA, relu, bf16 out ----------------
// grid (64, 8): x = m-block (XCD affinity), y = n-block
__global__ __launch_bounds__(256) void gemm_out(
        const short* __restrict__ A, const short* __restrict__ BT,
        const float* __restrict__ bias, short* __restrict__ C) {
    __shared__ __attribute__((aligned(16))) short As[128 * 64];
    __shared__ __attribute__((aligned(16))) short Bs[64 * 64];
    const int tid = threadIdx.x;
    const int w = tid >> 6, ln = tid & 63;
    const int quad = ln >> 4, col = ln & 15;
    const int m0 = blockIdx.x * 128;
    const int n0 = blockIdx.y * 64;
    const int wr = w >> 1, wc = w & 1;

    floatx4 acc[4][2];
#pragma unroll
    for (int i = 0; i < 4; i++)
#pragma unroll
        for (int j = 0; j < 2; j++) acc[i][j] = (floatx4)0.0f;

    for (int k0 = 0; k0 < 512; k0 += 64) {
        __syncthreads();
#pragma unroll
        for (int i = 0; i < 4; i++) {
            const int slot = i * 256 + tid;
            const int r = slot >> 3;
            const int c = (slot & 7) ^ (r & 7);
            gld_lds16(A + (size_t)(m0 + r) * 512 + k0 + c * 8, As + slot * 8);
        }
#pragma unroll
        for (int i = 0; i < 2; i++) {
            const int slot = i * 256 + tid;          // 512 chunks (64 rows)
            const int r = slot >> 3;
            const int c = (slot & 7) ^ (r & 7);
            gld_lds16(BT + (size_t)(n0 + r) * 512 + k0 + c * 8, Bs + slot * 8);
        }
        __syncthreads();
#pragma unroll
        for (int s = 0; s < 2; s++) {
            short8 af[4], bfr[2];
#pragma unroll
            for (int i = 0; i < 4; i++) {
                const int row = wr * 64 + i * 16 + col;
                const int cs = (s * 4 + quad) ^ (col & 7);
                af[i] = *(const short8*)&As[row * 64 + cs * 8];
            }
#pragma unroll
            for (int j = 0; j < 2; j++) {
                const int row = wc * 32 + j * 16 + col;
                const int cs = (s * 4 + quad) ^ (col & 7);
                bfr[j] = *(const short8*)&Bs[row * 64 + cs * 8];
            }
#pragma unroll
            for (int i = 0; i < 4; i++)
#pragma unroll
                for (int j = 0; j < 2; j++)
                    acc[i][j] = mfma16(af[i], bfr[j], acc[i][j]);
        }
    }

#pragma unroll
    for (int j = 0; j < 2; j++) {
        const int cc = n0 + wc * 32 + j * 16 + col;
        const float bj = bias[cc];
#pragma unroll
        for (int i = 0; i < 4; i++)
#pragma unroll
            for (int r = 0; r < 4; r++) {
                const int row = m0 + wr * 64 + i * 16 + quad * 4 + r;
                C[(size_t)row * 512 + cc] = f2bf(fmaxf(acc[i][j][r] + bj, 0.0f));
            }
    }
}

// ---------------- fused flash attention + residual (R7 structure) ----------------
__global__ __launch_bounds__(256) void attn_kernel(
        const short* __restrict__ Qp, const short* __restrict__ Kp,
        const short* __restrict__ Vt, short* __restrict__ Xo) {
    __shared__ __attribute__((aligned(16))) short Ks[2][64 * 64];
    __shared__ __attribute__((aligned(16))) short Vs[2][64 * 64];
    const int tid = threadIdx.x;
    const int w = tid >> 6, ln = tid & 63;
    const int quad = ln >> 4, col = ln & 15;
    const int gid = blockIdx.x;
    const int h = gid & 7;                  // XCD pin: one head per XCD
    const int rest = gid >> 3;              // 0..127
    const int b = rest >> 4;                // 0..7
    const int q0 = (rest & 15) * 64 + w * 16;
    const size_t baseQ = (size_t)b * NSEQ * DIM + (size_t)h * HD;
    const size_t baseV = (size_t)h * HD * NTOK + (size_t)b * NSEQ;
    const float sc = 1.44269504089f / 22.6274169979f;   // log2e / sqrt(512)

    const int slot0 = tid, slot1 = 256 + tid;
    const int r0 = slot0 >> 3, c0 = (slot0 & 7) ^ (r0 & 7);
    const int r1 = slot1 >> 3, c1 = (slot1 & 7) ^ (r1 & 7);
    const short* kp0 = Kp + baseQ + (size_t)r0 * DIM + c0 * 8;
    const short* kp1 = Kp + baseQ + (size_t)r1 * DIM + c1 * 8;
    const short* vp0 = Vt + baseV + (size_t)r0 * NTOK + c0 * 8;
    const short* vp1 = Vt + baseV + (size_t)r1 * NTOK + c1 * 8;
    const int ldsl0 = (w * 64) * 8;
    const int ldsl1 = (256 + w * 64) * 8;

    short8 qa[2];
#pragma unroll
    for (int s = 0; s < 2; s++) {
        short8 raw = *(const short8*)(Qp + baseQ + (size_t)(q0 + col) * DIM + s * 32 + quad * 8);
        short8 sq;
#pragma unroll
        for (int j = 0; j < 8; j++) sq[j] = f2bf(bf2f(raw[j]) * sc);
        qa[s] = sq;
    }

    floatx4 oacc[4];
#pragma unroll
    for (int dt = 0; dt < 4; dt++) oacc[dt] = (floatx4)0.0f;
    float lp = 0.0f;

    gld_lds16(kp0, &Ks[0][ldsl0]);
    gld_lds16(kp1, &Ks[0][ldsl1]);
    gld_lds16(vp0, &Vs[0][ldsl0]);
    gld_lds16(vp1, &Vs[0][ldsl1]);
    __syncthreads();

    for (int t = 0; t < 16; t++) {
        const int cur = t & 1;
        if (t < 15) {
            const int kn = (t + 1) * 64;
            const int nxt = cur ^ 1;
            gld_lds16(kp0 + (size_t)kn * DIM, &Ks[nxt][ldsl0]);
            gld_lds16(kp1 + (size_t)kn * DIM, &Ks[nxt][ldsl1]);
            gld_lds16(vp0 + kn, &Vs[nxt][ldsl0]);
            gld_lds16(vp1 + kn, &Vs[nxt][ldsl1]);
        }
        const short* Kc = Ks[cur];
        const short* Vc = Vs[cur];
#pragma unroll
        for (int nt = 0; nt < 4; nt++) {
            floatx4 z = (floatx4)0.0f;
#pragma unroll
            for (int s = 0; s < 2; s++) {
                const int cs = (s * 4 + quad) ^ (col & 7);
                const short8 kf = *(const short8*)&Kc[(nt * 16 + col) * 64 + cs * 8];
                z = mfma16(kf, qa[s], z);           // S^T tile
            }
            const float p0 = exp2f(z[0]), p1 = exp2f(z[1]);
            const float p2 = exp2f(z[2]), p3 = exp2f(z[3]);
            lp += (p0 + p1) + (p2 + p3);
            const unsigned lo = __builtin_amdgcn_perm(
                __builtin_bit_cast(unsigned, p1), __builtin_bit_cast(unsigned, p0), 0x07060302u);
            const unsigned hi = __builtin_amdgcn_perm(
                __builtin_bit_cast(unsigned, p3), __builtin_bit_cast(unsigned, p2), 0x07060302u);
            intx2 pd; pd.x = (int)lo; pd.y = (int)hi;
            const short4v pf = __builtin_bit_cast(short4v, pd);
#pragma unroll
            for (int dt = 0; dt < 4; dt++) {
                const int cs = (nt * 2 + (quad >> 1)) ^ (col & 7);
                const short4v vf = *(const short4v*)&Vc[(dt * 16 + col) * 64 + cs * 8 + (quad & 1) * 4];
                oacc[dt] = mfma_pv(pf, vf, oacc[dt]);
            }
        }
        __syncthreads();
    }

    lp += __shfl_xor(lp, 16);
    lp += __shfl_xor(lp, 32);
    float linv[4];
#pragma unroll
    for (int r = 0; r < 4; r++) linv[r] = 1.0f / __shfl(lp, quad * 4 + r);

#pragma unroll
    for (int dt = 0; dt < 4; dt++) {
#pragma unroll
        for (int r = 0; r < 4; r++) {
            const int q = q0 + quad * 4 + r;
            const size_t off = baseQ + (size_t)q * DIM + dt * 16 + col;
            Xo[off] = f2bf(oacc[dt][r] * linv[r] + bf2f(Qp[off]));
        }
    }
}

// ---------------- LayerNorm (wave per row), bf16 in, bf16 out ----------------
__global__ __launch_bounds__(256) void ln_kernel(
        const short* __restrict__ X, const float* __restrict__ g,
        const float* __restrict__ be, short* __restrict__ Yb) {
    const int row = blockIdx.x * 4 + (threadIdx.x >> 6);
    const int ln = threadIdx.x & 63;
    union { intx4 v; short s[8]; } u;
    u.v = *(const intx4*)(X + (size_t)row * DIM + ln * 8);
    float x[8];
#pragma unroll
    for (int j = 0; j < 8; j++) x[j] = bf2f(u.s[j]);
    float s = 0.f, q = 0.f;
#pragma unroll
    for (int j = 0; j < 8; j++) { s += x[j]; q += x[j] * x[j]; }
#pragma unroll
    for (int off = 1; off < 64; off <<= 1) {
        s += __shfl_xor(s, off);
        q += __shfl_xor(q, off);
    }
    const float mean = s * (1.0f / DIM);
    const float var = q * (1.0f / DIM) - mean * mean;
    const float rstd = rsqrtf(var + 1e-5f);
    const int c0 = ln * 8;
    union { intx4 v; short s[8]; } o;
#pragma unroll
    for (int j = 0; j < 8; j++)
        o.s[j] = f2bf((x[j] - mean) * rstd * g[c0 + j] + be[c0 + j]);
    *(intx4*)(Yb + (size_t)row * DIM + c0) = o.v;
}

// ---------------- final: out = LN1(Xln0 + Yrelu), bf16 ins, fp32 out ----------------
__global__ __launch_bounds__(256) void final_kernel(
        const short* __restrict__ Xr, const short* __restrict__ Yr,
        const float* __restrict__ g, const float* __restrict__ be,
        float* __restrict__ out) {
    const int row = blockIdx.x * 4 + (threadIdx.x >> 6);
    const int ln = threadIdx.x & 63;
    const size_t rb = (size_t)row * DIM;
    const int c0 = ln * 8;
    union { intx4 v; short s[8]; } ux, uy;
    ux.v = *(const intx4*)(Xr + rb + c0);
    uy.v = *(const intx4*)(Yr + rb + c0);
    float x[8];
#pragma unroll
    for (int j = 0; j < 8; j++) x[j] = bf2f(ux.s[j]) + bf2f(uy.s[j]);
    float s = 0.f, q = 0.f;
#pragma unroll
    for (int j = 0; j < 8; j++) { s += x[j]; q += x[j] * x[j]; }
#pragma unroll
    for (int off = 1; off < 64; off <<= 1) {
        s += __shfl_xor(s, off);
        q += __shfl_xor(q, off);
    }
    const float mean = s * (1.0f / DIM);
    const float var = q * (1.0f / DIM) - mean * mean;
    const float rstd = rsqrtf(var + 1e-5f);
    float4 f0, f1;
    f0.x = (x[0] - mean) * rstd * g[c0 + 0] + be[c0 + 0];
    f0.y = (x[1] - mean) * rstd * g[c0 + 1] + be[c0 + 1];
    f0.z = (x[2] - mean) * rstd * g[c0 + 2] + be[c0 + 2];
    f0.w = (x[3] - mean) * rstd * g[c0 + 3] + be[c0 + 3];
    f1.x = (x[4] - mean) * rstd * g[c0 + 4] + be[c0 + 4];
    f1.y = (x[5] - mean) * rstd * g[c0 + 5] + be[c0 + 5];
    f1.z = (x[6] - mean) * rstd * g[c0 + 6] + be[c0 + 6];
    f1.w = (x[7] - mean) * rstd * g[c0 + 7] + be[c0 + 7];
    *(float4*)(out + rb + c0)     = f0;
    *(float4*)(out + rb + c0 + 4) = f1;
}

extern "C" void kernel_launch(void* const* d_in, const int* in_sizes, int n_in,
                              void* d_out, int out_size, void* d_ws, size_t ws_size,
                              hipStream_t stream) {
    const float* Q  = (const float*)d_in[0];
    const float* K  = (const float*)d_in[1];
    const float* Wq = (const float*)d_in[2];
    const float* bq = (const float*)d_in[3];
    const float* Wk = (const float*)d_in[4];
    const float* bk = (const float*)d_in[5];
    const float* Wv = (const float*)d_in[6];
    const float* bv = (const float*)d_in[7];
    const float* Wo = (const float*)d_in[8];
    const float* bo = (const float*)d_in[9];
    const float* g0 = (const float*)d_in[10];
    const float* b0 = (const float*)d_in[11];
    const float* g1 = (const float*)d_in[12];
    const float* b1 = (const float*)d_in[13];
    float* out = (float*)d_out;

    const size_t NE = (size_t)NTOK * DIM;
    char* p = (char*)d_ws;
    short* Qb   = (short*)p; p += NE * 2;
    short* Kb   = (short*)p; p += NE * 2;
    short* WqT  = (short*)p; p += 512 * 512 * 2;
    short* WkT  = (short*)p; p += 512 * 512 * 2;
    short* WvT  = (short*)p; p += 512 * 512 * 2;
    short* WoT  = (short*)p; p += 512 * 512 * 2;
    short* Qpb  = (short*)p; p += NE * 2;
    short* Kpb  = (short*)p; p += NE * 2;
    short* Vt   = (short*)p; p += NE * 2;   // [dv=512][tok=8192]
    short* Xat  = (short*)p; p += NE * 2;   // attn out + residual, bf16
    short* Xl0b = (short*)p; p += NE * 2;   // LN0 out, bf16
    short* Yob  = (short*)p; p += NE * 2;   // relu(out-proj), bf16

    prep_kernel<<<8448, 256, 0, stream>>>(Q, K, Wq, Wk, Wv, Wo,
                                          Qb, Kb, WqT, WkT, WvT, WoT);
    proj_kernel<<<dim3(64, 12), 256, 0, stream>>>(Qb, Kb, WqT, WkT, WvT,
                                                  bq, bk, bv, Qpb, Kpb, Vt);
    attn_kernel<<<1024, 256, 0, stream>>>(Qpb, Kpb, Vt, Xat);
    ln_kernel<<<2048, 256, 0, stream>>>(Xat, g0, b0, Xl0b);
    gemm_out<<<dim3(64, 8), 256, 0, stream>>>(Xl0b, WoT, bo, Yob);
    final_kernel<<<2048, 256, 0, stream>>>(Xl0b, Yob, g1, b1, out);
}

// Round 9
// 193.623 us; speedup vs baseline: 1.1006x; 1.0134x over previous
//
#include <hip/hip_runtime.h>
#include <hip/hip_bf16.h>

#define DIM   512
#define NSEQ  1024
#define NB    8
#define NH    8
#define HD    64
#define NTOK  8192   // NB*NSEQ

typedef __attribute__((ext_vector_type(8))) short  short8;
typedef __attribute__((ext_vector_type(4))) short  short4v;
typedef __attribute__((ext_vector_type(4))) float  floatx4;
typedef __attribute__((ext_vector_type(4))) int    intx4;
typedef __attribute__((ext_vector_type(2))) int    intx2;
typedef __attribute__((ext_vector_type(8))) __bf16 bf16x8;

__device__ inline short f2bf(float x) {
    union { float f; unsigned u; } c; c.f = x;
    unsigned r = c.u + 0x7fffu + ((c.u >> 16) & 1u);
    return (short)(r >> 16);
}
__device__ inline float bf2f(short s) {
    union { unsigned u; float f; } c; c.u = ((unsigned)(unsigned short)s) << 16;
    return c.f;
}
__device__ inline floatx4 mfma16(short8 a, short8 b, floatx4 c) {
    return __builtin_amdgcn_mfma_f32_16x16x32_bf16(
        __builtin_bit_cast(bf16x8, a), __builtin_bit_cast(bf16x8, b), c, 0, 0, 0);
}
__device__ inline floatx4 mfma_pv(short4v a, short4v b, floatx4 c) {
#if __has_builtin(__builtin_amdgcn_mfma_f32_16x16x16bf16_1k)
    return __builtin_amdgcn_mfma_f32_16x16x16bf16_1k(a, b, c, 0, 0, 0);
#else
    asm("v_mfma_f32_16x16x16_bf16 %0, %1, %2, %0" : "+v"(c) : "v"(a), "v"(b));
    return c;
#endif
}
__device__ inline void gld_lds16(const void* g, void* l) {
    __builtin_amdgcn_global_load_lds(
        (__attribute__((address_space(1))) void*)(g),
        (__attribute__((address_space(3))) void*)(l), 16, 0, 0);
}

// ---------------- prep: cast Q,K -> bf16 (blocks 0..8191) + tiled W transpose ----------------
__global__ __launch_bounds__(256) void prep_kernel(
        const float* __restrict__ Q, const float* __restrict__ K,
        const float* __restrict__ Wq, const float* __restrict__ Wk,
        const float* __restrict__ Wv, const float* __restrict__ Wo,
        short* __restrict__ Qb, short* __restrict__ Kb,
        short* __restrict__ WqT, short* __restrict__ WkT,
        short* __restrict__ WvT, short* __restrict__ WoT) {
    const int tid = threadIdx.x;
    if (blockIdx.x < 8192) {
        const int idx = blockIdx.x * 256 + tid;     // quads of 4 floats
        const float* src; short* dst; int qi;
        if (idx < 1048576) { src = Q; dst = Qb; qi = idx; }
        else               { src = K; dst = Kb; qi = idx - 1048576; }
        const float4 v = *(const float4*)(src + (size_t)qi * 4);
        short4v o;
        o.x = f2bf(v.x); o.y = f2bf(v.y); o.z = f2bf(v.z); o.w = f2bf(v.w);
        *(short4v*)(dst + (size_t)qi * 4) = o;
        return;
    }
    // transpose: 64x64 tiles, 64 tiles per W, 4 W's -> 256 blocks
    __shared__ short Ts[64 * 65];
    const int b = blockIdx.x - 8192;
    const int wsel = b >> 6, tile = b & 63;
    const int tr = (tile >> 3) * 64;                // k base
    const int tc = (tile & 7) * 64;                 // n base
    const float* src = (wsel == 0) ? Wq : (wsel == 1) ? Wk : (wsel == 2) ? Wv : Wo;
    short* dst       = (wsel == 0) ? WqT : (wsel == 1) ? WkT : (wsel == 2) ? WvT : WoT;
#pragma unroll
    for (int i = 0; i < 16; i++) {
        const int idx = i * 256 + tid;              // over 64x64
        const int r = idx >> 6, c = idx & 63;       // coalesced read
        Ts[c * 65 + r] = f2bf(src[(size_t)(tr + r) * 512 + tc + c]);
    }
    __syncthreads();
#pragma unroll
    for (int i = 0; i < 16; i++) {
        const int idx = i * 256 + tid;
        const int n = idx >> 6, k = idx & 63;       // coalesced write
        dst[(size_t)(tc + n) * 512 + tr + k] = Ts[n * 65 + k];
    }
}

// ---------------- fused QKV projection GEMM, BK=64, swizzled DMA staging ----------------
// grid (64, 12): x = m-block (XCD-affinity for A tiles), y: sel = y>>2
__global__ __launch_bounds__(256) void proj_kernel(
        const short* __restrict__ Qb, const short* __restrict__ Kb,
        const short* __restrict__ WqT, const short* __restrict__ WkT,
        const short* __restrict__ WvT,
        const float* __restrict__ bq, const float* __restrict__ bk,
        const float* __restrict__ bv,
        short* __restrict__ Qpb, short* __restrict__ Kpb,
        short* __restrict__ Vt) {
    __shared__ __attribute__((aligned(16))) short smem[16384]; // As 8192 + Bs 8192; Ts aliases
    short* As = smem;
    short* Bs = smem + 8192;
    const int tid = threadIdx.x;
    const int w = tid >> 6, ln = tid & 63;
    const int quad = ln >> 4, col = ln & 15;
    const int nb = blockIdx.y;
    const int sel = nb >> 2;
    const int n0 = (nb & 3) * 128;
    const int m0 = blockIdx.x * 128;
    const int wr = w >> 1, wc = w & 1;
    const short* A    = (sel == 0) ? Qb : Kb;
    const short* BT   = (sel == 0) ? WqT : (sel == 1) ? WkT : WvT;
    const float* bias = (sel == 0) ? bq : (sel == 1) ? bk : bv;

    floatx4 acc[4][4];
#pragma unroll
    for (int i = 0; i < 4; i++)
#pragma unroll
        for (int j = 0; j < 4; j++) acc[i][j] = (floatx4)0.0f;

    for (int k0 = 0; k0 < 512; k0 += 64) {
        __syncthreads();
#pragma unroll
        for (int i = 0; i < 4; i++) {
            const int slot = i * 256 + tid;          // 1024 chunks of 16B
            const int r = slot >> 3;                 // tile row 0..127
            const int c = (slot & 7) ^ (r & 7);      // swizzled source chunk
            gld_lds16(A  + (size_t)(m0 + r) * 512 + k0 + c * 8, As + slot * 8);
            gld_lds16(BT + (size_t)(n0 + r) * 512 + k0 + c * 8, Bs + slot * 8);
        }
        __syncthreads();
#pragma unroll
        for (int s = 0; s < 2; s++) {
            short8 af[4], bfr[4];
#pragma unroll
            for (int i = 0; i < 4; i++) {
                const int row = wr * 64 + i * 16 + col;
                const int cs = (s * 4 + quad) ^ (col & 7);
                af[i] = *(const short8*)&As[row * 64 + cs * 8];
            }
#pragma unroll
            for (int j = 0; j < 4; j++) {
                const int row = wc * 64 + j * 16 + col;
                const int cs = (s * 4 + quad) ^ (col & 7);
                bfr[j] = *(const short8*)&Bs[row * 64 + cs * 8];
            }
#pragma unroll
            for (int i = 0; i < 4; i++)
#pragma unroll
                for (int j = 0; j < 4; j++)
                    acc[i][j] = mfma16(af[i], bfr[j], acc[i][j]);
        }
    }

    if (sel < 2) {
        short* C = (sel == 0) ? Qpb : Kpb;
#pragma unroll
        for (int j = 0; j < 4; j++) {
            const int cc = n0 + wc * 64 + j * 16 + col;
            const float bj = bias[cc];
#pragma unroll
            for (int i = 0; i < 4; i++)
#pragma unroll
                for (int r = 0; r < 4; r++) {
                    const int row = m0 + wr * 64 + i * 16 + quad * 4 + r;
                    C[(size_t)row * 512 + cc] = f2bf(acc[i][j][r] + bj);
                }
        }
    } else {
        // transposed epilogue: Vt[dv][tok], two 64-col halves through LDS
        short* Ts = smem;                            // 64 x 136
        const int dvl = tid >> 2;
        const int tch = (tid & 3) * 32;
#pragma unroll
        for (int hc = 0; hc < 2; hc++) {
            __syncthreads();
            if (wc == hc) {
#pragma unroll
                for (int j = 0; j < 4; j++) {
                    const float bj = bias[n0 + hc * 64 + j * 16 + col];
#pragma unroll
                    for (int i = 0; i < 4; i++)
#pragma unroll
                        for (int r = 0; r < 4; r++)
                            Ts[(j * 16 + col) * 136 + wr * 64 + i * 16 + quad * 4 + r] =
                                f2bf(acc[i][j][r] + bj);
                }
            }
            __syncthreads();
#pragma unroll
            for (int u = 0; u < 4; u++)
                *(intx4*)(Vt + (size_t)(n0 + hc * 64 + dvl) * NTOK + m0 + tch + u * 8) =
                    *(const intx4*)&Ts[dvl * 136 + tch + u * 8];
        }
    }
}

// ---------------- out-proj GEMM: 128x64 tile, BK=64, swizzled DMA, relu, bf16 out ----------------
// grid (64, 8): x = m-block (XCD affinity), y = n-block
__global__ __launch_bounds__(256) void gemm_out(
        const short* __restrict__ A, const short* __restrict__ BT,
        const float* __restrict__ bias, short* __restrict__ C) {
    __shared__ __attribute__((aligned(16))) short As[128 * 64];
    __shared__ __attribute__((aligned(16))) short Bs[64 * 64];
    const int tid = threadIdx.x;
    const int w = tid >> 6, ln = tid & 63;
    const int quad = ln >> 4, col = ln & 15;
    const int m0 = blockIdx.x * 128;
    const int n0 = blockIdx.y * 64;
    const int wr = w >> 1, wc = w & 1;

    floatx4 acc[4][2];
#pragma unroll
    for (int i = 0; i < 4; i++)
#pragma unroll
        for (int j = 0; j < 2; j++) acc[i][j] = (floatx4)0.0f;

    for (int k0 = 0; k0 < 512; k0 += 64) {
        __syncthreads();
#pragma unroll
        for (int i = 0; i < 4; i++) {
            const int slot = i * 256 + tid;
            const int r = slot >> 3;
            const int c = (slot & 7) ^ (r & 7);
            gld_lds16(A + (size_t)(m0 + r) * 512 + k0 + c * 8, As + slot * 8);
        }
#pragma unroll
        for (int i = 0; i < 2; i++) {
            const int slot = i * 256 + tid;          // 512 chunks (64 rows)
            const int r = slot >> 3;
            const int c = (slot & 7) ^ (r & 7);
            gld_lds16(BT + (size_t)(n0 + r) * 512 + k0 + c * 8, Bs + slot * 8);
        }
        __syncthreads();
#pragma unroll
        for (int s = 0; s < 2; s++) {
            short8 af[4], bfr[2];
#pragma unroll
            for (int i = 0; i < 4; i++) {
                const int row = wr * 64 + i * 16 + col;
                const int cs = (s * 4 + quad) ^ (col & 7);
                af[i] = *(const short8*)&As[row * 64 + cs * 8];
            }
#pragma unroll
            for (int j = 0; j < 2; j++) {
                const int row = wc * 32 + j * 16 + col;
                const int cs = (s * 4 + quad) ^ (col & 7);
                bfr[j] = *(const short8*)&Bs[row * 64 + cs * 8];
            }
#pragma unroll
            for (int i = 0; i < 4; i++)
#pragma unroll
                for (int j = 0; j < 2; j++)
                    acc[i][j] = mfma16(af[i], bfr[j], acc[i][j]);
        }
    }

#pragma unroll
    for (int j = 0; j < 2; j++) {
        const int cc = n0 + wc * 32 + j * 16 + col;
        const float bj = bias[cc];
#pragma unroll
        for (int i = 0; i < 4; i++)
#pragma unroll
            for (int r = 0; r < 4; r++) {
                const int row = m0 + wr * 64 + i * 16 + quad * 4 + r;
                C[(size_t)row * 512 + cc] = f2bf(fmaxf(acc[i][j][r] + bj, 0.0f));
            }
    }
}

// ---------------- fused flash attention + residual ----------------
// 512 thr (8 waves), q-tile 128, KT=128: barriers/block 16->8, per-(b,h) K/V
// L2 traffic halved (8 waves share each staged tile). Grid 512 = 2 blocks/CU
// x 8 waves = 16 waves/CU (the proven R5/R7 operating point). DMA staging
// with source-side XOR swizzle; all LDS reads <=2-way (free) per quarter-wave.
__global__ __launch_bounds__(512) void attn_kernel(
        const short* __restrict__ Qp, const short* __restrict__ Kp,
        const short* __restrict__ Vt, short* __restrict__ Xo) {
    __shared__ __attribute__((aligned(16))) short Ks[2][128 * 64];
    __shared__ __attribute__((aligned(16))) short Vs[2][64 * 128];
    const int tid = threadIdx.x;
    const int w = tid >> 6, ln = tid & 63;
    const int quad = ln >> 4, col = ln & 15;
    const int gid = blockIdx.x;
    const int h = gid & 7;                  // XCD pin: one head per XCD
    const int rest = gid >> 3;              // 0..63
    const int b = rest >> 3;                // 0..7
    const int qt = rest & 7;                // 0..7
    const int q0 = qt * 128 + w * 16;
    const size_t baseQ = (size_t)b * NSEQ * DIM + (size_t)h * HD;
    const size_t baseV = (size_t)h * HD * NTOK + (size_t)b * NSEQ;
    const float sc = 1.44269504089f / 22.6274169979f;   // log2e / sqrt(512)

    // K staging: 1024 chunks (128 rows x 8), slot = i*512+tid
    //   r = slot>>3, source chunk ck = (slot&7) ^ (r&7)
    // V staging: 1024 chunks (64 rows x 16), r = slot>>4, cv = (slot&15) ^ (r&15)
    const int ks0 = tid, ks1 = 512 + tid;
    const int kr0 = ks0 >> 3, kc0 = (ks0 & 7) ^ (kr0 & 7);
    const int kr1 = ks1 >> 3, kc1 = (ks1 & 7) ^ (kr1 & 7);
    const int vr0 = ks0 >> 4, vc0 = (ks0 & 15) ^ (vr0 & 15);
    const int vr1 = ks1 >> 4, vc1 = (ks1 & 15) ^ (vr1 & 15);
    const short* kp0 = Kp + baseQ + (size_t)kr0 * DIM + kc0 * 8;
    const short* kp1 = Kp + baseQ + (size_t)kr1 * DIM + kc1 * 8;
    const short* vp0 = Vt + baseV + (size_t)vr0 * NTOK + vc0 * 8;
    const short* vp1 = Vt + baseV + (size_t)vr1 * NTOK + vc1 * 8;
    // wave-uniform LDS dest bases (HW adds lane*16); slot block = i*512 + w*64
    const int ldsl0 = (w * 64) * 8;
    const int ldsl1 = (512 + w * 64) * 8;

    // Q fragments (B-operand), pre-scaled once
    short8 qa[2];
#pragma unroll
    for (int s = 0; s < 2; s++) {
        short8 raw = *(const short8*)(Qp + baseQ + (size_t)(q0 + col) * DIM + s * 32 + quad * 8);
        short8 sq;
#pragma unroll
        for (int j = 0; j < 8; j++) sq[j] = f2bf(bf2f(raw[j]) * sc);
        qa[s] = sq;
    }

    floatx4 oacc[4];
#pragma unroll
    for (int dt = 0; dt < 4; dt++) oacc[dt] = (floatx4)0.0f;
    float lp = 0.0f;

    // prologue: DMA tile 0 into buffer 0
    gld_lds16(kp0, &Ks[0][ldsl0]);
    gld_lds16(kp1, &Ks[0][ldsl1]);
    gld_lds16(vp0, &Vs[0][ldsl0]);
    gld_lds16(vp1, &Vs[0][ldsl1]);
    __syncthreads();

    for (int t = 0; t < 8; t++) {
        const int cur = t & 1;
        if (t < 7) {
            const int kn = (t + 1) * 128;    // K advances by rows, V by cols
            const int nxt = cur ^ 1;
            gld_lds16(kp0 + (size_t)kn * DIM, &Ks[nxt][ldsl0]);
            gld_lds16(kp1 + (size_t)kn * DIM, &Ks[nxt][ldsl1]);
            gld_lds16(vp0 + kn, &Vs[nxt][ldsl0]);
            gld_lds16(vp1 + kn, &Vs[nxt][ldsl1]);
        }
        const short* Kc = Ks[cur];
        const short* Vc = Vs[cur];
#pragma unroll
        for (int nt = 0; nt < 8; nt++) {
            floatx4 z = (floatx4)0.0f;
#pragma unroll
            for (int s = 0; s < 2; s++) {
                const int cs = (s * 4 + quad) ^ (col & 7);
                const short8 kf = *(const short8*)&Kc[(nt * 16 + col) * 64 + cs * 8];
                z = mfma16(kf, qa[s], z);           // S^T tile
            }
            const float p0 = exp2f(z[0]), p1 = exp2f(z[1]);
            const float p2 = exp2f(z[2]), p3 = exp2f(z[3]);
            lp += (p0 + p1) + (p2 + p3);
            const unsigned lo = __builtin_amdgcn_perm(
                __builtin_bit_cast(unsigned, p1), __builtin_bit_cast(unsigned, p0), 0x07060302u);
            const unsigned hi = __builtin_amdgcn_perm(
                __builtin_bit_cast(unsigned, p3), __builtin_bit_cast(unsigned, p2), 0x07060302u);
            intx2 pd; pd.x = (int)lo; pd.y = (int)hi;
            const short4v pf = __builtin_bit_cast(short4v, pd);
#pragma unroll
            for (int dt = 0; dt < 4; dt++) {
                const int cs = (nt * 2 + (quad >> 1)) ^ col;
                const short4v vf = *(const short4v*)&Vc[(dt * 16 + col) * 128 + cs * 8 + (quad & 1) * 4];
                oacc[dt] = mfma_pv(pf, vf, oacc[dt]);
            }
        }
        __syncthreads();
    }

    lp += __shfl_xor(lp, 16);
    lp += __shfl_xor(lp, 32);
    float linv[4];
#pragma unroll
    for (int r = 0; r < 4; r++) linv[r] = 1.0f / __shfl(lp, quad * 4 + r);

#pragma unroll
    for (int dt = 0; dt < 4; dt++) {
#pragma unroll
        for (int r = 0; r < 4; r++) {
            const int q = q0 + quad * 4 + r;
            const size_t off = baseQ + (size_t)q * DIM + dt * 16 + col;
            Xo[off] = f2bf(oacc[dt][r] * linv[r] + bf2f(Qp[off]));
        }
    }
}

// ---------------- LayerNorm (wave per row), bf16 in, bf16 out ----------------
__global__ __launch_bounds__(256) void ln_kernel(
        const short* __restrict__ X, const float* __restrict__ g,
        const float* __restrict__ be, short* __restrict__ Yb) {
    const int row = blockIdx.x * 4 + (threadIdx.x >> 6);
    const int ln = threadIdx.x & 63;
    union { intx4 v; short s[8]; } u;
    u.v = *(const intx4*)(X + (size_t)row * DIM + ln * 8);
    float x[8];
#pragma unroll
    for (int j = 0; j < 8; j++) x[j] = bf2f(u.s[j]);
    float s = 0.f, q = 0.f;
#pragma unroll
    for (int j = 0; j < 8; j++) { s += x[j]; q += x[j] * x[j]; }
#pragma unroll
    for (int off = 1; off < 64; off <<= 1) {
        s += __shfl_xor(s, off);
        q += __shfl_xor(q, off);
    }
    const float mean = s * (1.0f / DIM);
    const float var = q * (1.0f / DIM) - mean * mean;
    const float rstd = rsqrtf(var + 1e-5f);
    const int c0 = ln * 8;
    union { intx4 v; short s[8]; } o;
#pragma unroll
    for (int j = 0; j < 8; j++)
        o.s[j] = f2bf((x[j] - mean) * rstd * g[c0 + j] + be[c0 + j]);
    *(intx4*)(Yb + (size_t)row * DIM + c0) = o.v;
}

// ---------------- final: out = LN1(Xln0 + Yrelu), bf16 ins, fp32 out ----------------
__global__ __launch_bounds__(256) void final_kernel(
        const short* __restrict__ Xr, const short* __restrict__ Yr,
        const float* __restrict__ g, const float* __restrict__ be,
        float* __restrict__ out) {
    const int row = blockIdx.x * 4 + (threadIdx.x >> 6);
    const int ln = threadIdx.x & 63;
    const size_t rb = (size_t)row * DIM;
    const int c0 = ln * 8;
    union { intx4 v; short s[8]; } ux, uy;
    ux.v = *(const intx4*)(Xr + rb + c0);
    uy.v = *(const intx4*)(Yr + rb + c0);
    float x[8];
#pragma unroll
    for (int j = 0; j < 8; j++) x[j] = bf2f(ux.s[j]) + bf2f(uy.s[j]);
    float s = 0.f, q = 0.f;
#pragma unroll
    for (int j = 0; j < 8; j++) { s += x[j]; q += x[j] * x[j]; }
#pragma unroll
    for (int off = 1; off < 64; off <<= 1) {
        s += __shfl_xor(s, off);
        q += __shfl_xor(q, off);
    }
    const float mean = s * (1.0f / DIM);
    const float var = q * (1.0f / DIM) - mean * mean;
    const float rstd = rsqrtf(var + 1e-5f);
    float4 f0, f1;
    f0.x = (x[0] - mean) * rstd * g[c0 + 0] + be[c0 + 0];
    f0.y = (x[1] - mean) * rstd * g[c0 + 1] + be[c0 + 1];
    f0.z = (x[2] - mean) * rstd * g[c0 + 2] + be[c0 + 2];
    f0.w = (x[3] - mean) * rstd * g[c0 + 3] + be[c0 + 3];
    f1.x = (x[4] - mean) * rstd * g[c0 + 4] + be[c0 + 4];
    f1.y = (x[5] - mean) * rstd * g[c0 + 5] + be[c0 + 5];
    f1.z = (x[6] - mean) * rstd * g[c0 + 6] + be[c0 + 6];
    f1.w = (x[7] - mean) * rstd * g[c0 + 7] + be[c0 + 7];
    *(float4*)(out + rb + c0)     = f0;
    *(float4*)(out + rb + c0 + 4) = f1;
}

extern "C" void kernel_launch(void* const* d_in, const int* in_sizes, int n_in,
                              void* d_out, int out_size, void* d_ws, size_t ws_size,
                              hipStream_t stream) {
    const float* Q  = (const float*)d_in[0];
    const float* K  = (const float*)d_in[1];
    const float* Wq = (const float*)d_in[2];
    const float* bq = (const float*)d_in[3];
    const float* Wk = (const float*)d_in[4];
    const float* bk = (const float*)d_in[5];
    const float* Wv = (const float*)d_in[6];
    const float* bv = (const float*)d_in[7];
    const float* Wo = (const float*)d_in[8];
    const float* bo = (const float*)d_in[9];
    const float* g0 = (const float*)d_in[10];
    const float* b0 = (const float*)d_in[11];
    const float* g1 = (const float*)d_in[12];
    const float* b1 = (const float*)d_in[13];
    float* out = (float*)d_out;

    const size_t NE = (size_t)NTOK * DIM;
    char* p = (char*)d_ws;
    short* Qb   = (short*)p; p += NE * 2;
    short* Kb   = (short*)p; p += NE * 2;
    short* WqT  = (short*)p; p += 512 * 512 * 2;
    short* WkT  = (short*)p; p += 512 * 512 * 2;
    short* WvT  = (short*)p; p += 512 * 512 * 2;
    short* WoT  = (short*)p; p += 512 * 512 * 2;
    short* Qpb  = (short*)p; p += NE * 2;
    short* Kpb  = (short*)p; p += NE * 2;
    short* Vt   = (short*)p; p += NE * 2;   // [dv=512][tok=8192]
    short* Xat  = (short*)p; p += NE * 2;   // attn out + residual, bf16
    short* Xl0b = (short*)p; p += NE * 2;   // LN0 out, bf16
    short* Yob  = (short*)p; p += NE * 2;   // relu(out-proj), bf16

    prep_kernel<<<8448, 256, 0, stream>>>(Q, K, Wq, Wk, Wv, Wo,
                                          Qb, Kb, WqT, WkT, WvT, WoT);
    proj_kernel<<<dim3(64, 12), 256, 0, stream>>>(Qb, Kb, WqT, WkT, WvT,
                                                  bq, bk, bv, Qpb, Kpb, Vt);
    attn_kernel<<<512, 512, 0, stream>>>(Qpb, Kpb, Vt, Xat);
    ln_kernel<<<2048, 256, 0, stream>>>(Xat, g0, b0, Xl0b);
    gemm_out<<<dim3(64, 8), 256, 0, stream>>>(Xl0b, WoT, bo, Yob);
    final_kernel<<<2048, 256, 0, stream>>>(Xl0b, Yob, g1, b1, out);
}

// Round 10
// 186.640 us; speedup vs baseline: 1.1418x; 1.0374x over previous
//
#include <hip/hip_runtime.h>
#include <hip/hip_bf16.h>

#define DIM   512
#define NSEQ  1024
#define NB    8
#define NH    8
#define HD    64
#define NTOK  8192   // NB*NSEQ

typedef __attribute__((ext_vector_type(8))) short  short8;
typedef __attribute__((ext_vector_type(4))) short  short4v;
typedef __attribute__((ext_vector_type(4))) float  floatx4;
typedef __attribute__((ext_vector_type(4))) int    intx4;
typedef __attribute__((ext_vector_type(2))) int    intx2;
typedef __attribute__((ext_vector_type(8))) __bf16 bf16x8;

__device__ inline short f2bf(float x) {
    union { float f; unsigned u; } c; c.f = x;
    unsigned r = c.u + 0x7fffu + ((c.u >> 16) & 1u);
    return (short)(r >> 16);
}
__device__ inline float bf2f(short s) {
    union { unsigned u; float f; } c; c.u = ((unsigned)(unsigned short)s) << 16;
    return c.f;
}
// truncate-pack two fp32 -> two bf16 in one v_perm (bias negligible at our margins)
__device__ inline unsigned pkbf(float hi, float lo) {
    return __builtin_amdgcn_perm(
        __builtin_bit_cast(unsigned, hi), __builtin_bit_cast(unsigned, lo), 0x07060302u);
}
__device__ inline floatx4 mfma16(short8 a, short8 b, floatx4 c) {
    return __builtin_amdgcn_mfma_f32_16x16x32_bf16(
        __builtin_bit_cast(bf16x8, a), __builtin_bit_cast(bf16x8, b), c, 0, 0, 0);
}
__device__ inline floatx4 mfma_pv(short4v a, short4v b, floatx4 c) {
#if __has_builtin(__builtin_amdgcn_mfma_f32_16x16x16bf16_1k)
    return __builtin_amdgcn_mfma_f32_16x16x16bf16_1k(a, b, c, 0, 0, 0);
#else
    asm("v_mfma_f32_16x16x16_bf16 %0, %1, %2, %0" : "+v"(c) : "v"(a), "v"(b));
    return c;
#endif
}
__device__ inline void gld_lds16(const void* g, void* l) {
    __builtin_amdgcn_global_load_lds(
        (__attribute__((address_space(1))) void*)(g),
        (__attribute__((address_space(3))) void*)(l), 16, 0, 0);
}

// ---------------- prep: tiled W transpose only (256 blocks) ----------------
__global__ __launch_bounds__(256) void prep_kernel(
        const float* __restrict__ Wq, const float* __restrict__ Wk,
        const float* __restrict__ Wv, const float* __restrict__ Wo,
        short* __restrict__ WqT, short* __restrict__ WkT,
        short* __restrict__ WvT, short* __restrict__ WoT) {
    const int tid = threadIdx.x;
    __shared__ short Ts[64 * 65];
    const int b = blockIdx.x;
    const int wsel = b >> 6, tile = b & 63;
    const int tr = (tile >> 3) * 64;                // k base
    const int tc = (tile & 7) * 64;                 // n base
    const float* src = (wsel == 0) ? Wq : (wsel == 1) ? Wk : (wsel == 2) ? Wv : Wo;
    short* dst       = (wsel == 0) ? WqT : (wsel == 1) ? WkT : (wsel == 2) ? WvT : WoT;
#pragma unroll
    for (int i = 0; i < 16; i++) {
        const int idx = i * 256 + tid;              // over 64x64
        const int r = idx >> 6, c = idx & 63;       // coalesced read
        Ts[c * 65 + r] = f2bf(src[(size_t)(tr + r) * 512 + tc + c]);
    }
    __syncthreads();
#pragma unroll
    for (int i = 0; i < 16; i++) {
        const int idx = i * 256 + tid;
        const int n = idx >> 6, k = idx & 63;       // coalesced write
        dst[(size_t)(tc + n) * 512 + tr + k] = Ts[n * 65 + k];
    }
}

// ---------------- fused QKV projection GEMM, BK=64, fp32-A DMA staging ----------------
// grid (64, 12): x = m-block, y: sel = y>>2 {0:Q->Qpb, 1:K->Kpb, 2:K->Vt}.
// A staged as RAW fp32 (cast fused: bf16 fragments built with v_perm truncation).
// Source-side XOR swizzles: A chunks c^(r&15) (16 chunks/row), B chunks c^(r&7).
__global__ __launch_bounds__(256) void proj_kernel(
        const float* __restrict__ Qf, const float* __restrict__ Kf,
        const short* __restrict__ WqT, const short* __restrict__ WkT,
        const short* __restrict__ WvT,
        const float* __restrict__ bq, const float* __restrict__ bk,
        const float* __restrict__ bv,
        short* __restrict__ Qpb, short* __restrict__ Kpb,
        short* __restrict__ Vt) {
    __shared__ __attribute__((aligned(16))) char raw[49152]; // Af 32K + Bs 16K; Ts aliases
    float* Af = (float*)raw;                 // 128 x 64 fp32
    short* Bs = (short*)(raw + 32768);       // 128 x 64 bf16
    const int tid = threadIdx.x;
    const int w = tid >> 6, ln = tid & 63;
    const int quad = ln >> 4, col = ln & 15;
    const int nb = blockIdx.y;
    const int sel = nb >> 2;
    const int n0 = (nb & 3) * 128;
    const int m0 = blockIdx.x * 128;
    const int wr = w >> 1, wc = w & 1;
    const float* A    = (sel == 0) ? Qf : Kf;
    const short* BT   = (sel == 0) ? WqT : (sel == 1) ? WkT : WvT;
    const float* bias = (sel == 0) ? bq : (sel == 1) ? bk : bv;

    floatx4 acc[4][4];
#pragma unroll
    for (int i = 0; i < 4; i++)
#pragma unroll
        for (int j = 0; j < 4; j++) acc[i][j] = (floatx4)0.0f;

    for (int k0 = 0; k0 < 512; k0 += 64) {
        __syncthreads();
        // A: 2048 chunks of 16B (4 floats); slot -> r=slot>>4, c=(slot&15)^(r&15)
#pragma unroll
        for (int i = 0; i < 8; i++) {
            const int slot = i * 256 + tid;
            const int r = slot >> 4;
            const int c = (slot & 15) ^ (r & 15);
            gld_lds16(A + (size_t)(m0 + r) * 512 + k0 + c * 4, Af + slot * 4);
        }
        // B: 1024 chunks of 16B (8 bf16); slot -> r=slot>>3, c=(slot&7)^(r&7)
#pragma unroll
        for (int i = 0; i < 4; i++) {
            const int slot = i * 256 + tid;
            const int r = slot >> 3;
            const int c = (slot & 7) ^ (r & 7);
            gld_lds16(BT + (size_t)(n0 + r) * 512 + k0 + c * 8, Bs + slot * 8);
        }
        __syncthreads();
#pragma unroll
        for (int s = 0; s < 2; s++) {
            const int j2 = 2 * (s * 4 + quad);       // first of 2 consecutive chunks
            short8 af[4], bfr[4];
#pragma unroll
            for (int i = 0; i < 4; i++) {
                const int row = wr * 64 + i * 16 + col;
                const int cs0 = j2 ^ (row & 15);
                const int cs1 = (j2 + 1) ^ (row & 15);
                const floatx4 f0 = *(const floatx4*)&Af[row * 64 + cs0 * 4];
                const floatx4 f1 = *(const floatx4*)&Af[row * 64 + cs1 * 4];
                intx4 pk;
                pk.x = (int)pkbf(f0[1], f0[0]);
                pk.y = (int)pkbf(f0[3], f0[2]);
                pk.z = (int)pkbf(f1[1], f1[0]);
                pk.w = (int)pkbf(f1[3], f1[2]);
                af[i] = __builtin_bit_cast(short8, pk);
            }
#pragma unroll
            for (int j = 0; j < 4; j++) {
                const int row = wc * 64 + j * 16 + col;
                const int cs = (s * 4 + quad) ^ (col & 7);
                bfr[j] = *(const short8*)&Bs[row * 64 + cs * 8];
            }
#pragma unroll
            for (int i = 0; i < 4; i++)
#pragma unroll
                for (int j = 0; j < 4; j++)
                    acc[i][j] = mfma16(af[i], bfr[j], acc[i][j]);
        }
    }

    if (sel < 2) {
        short* C = (sel == 0) ? Qpb : Kpb;
#pragma unroll
        for (int j = 0; j < 4; j++) {
            const int cc = n0 + wc * 64 + j * 16 + col;
            const float bj = bias[cc];
#pragma unroll
            for (int i = 0; i < 4; i++)
#pragma unroll
                for (int r = 0; r < 4; r++) {
                    const int row = m0 + wr * 64 + i * 16 + quad * 4 + r;
                    C[(size_t)row * 512 + cc] = f2bf(acc[i][j][r] + bj);
                }
        }
    } else {
        // transposed epilogue: Vt[dv][tok], two 64-col halves through LDS
        short* Ts = (short*)raw;                     // 64 x 136 = 17408 B
        const int dvl = tid >> 2;
        const int tch = (tid & 3) * 32;
#pragma unroll
        for (int hc = 0; hc < 2; hc++) {
            __syncthreads();
            if (wc == hc) {
#pragma unroll
                for (int j = 0; j < 4; j++) {
                    const float bj = bias[n0 + hc * 64 + j * 16 + col];
#pragma unroll
                    for (int i = 0; i < 4; i++)
#pragma unroll
                        for (int r = 0; r < 4; r++)
                            Ts[(j * 16 + col) * 136 + wr * 64 + i * 16 + quad * 4 + r] =
                                f2bf(acc[i][j][r] + bj);
                }
            }
            __syncthreads();
#pragma unroll
            for (int u = 0; u < 4; u++)
                *(intx4*)(Vt + (size_t)(n0 + hc * 64 + dvl) * NTOK + m0 + tch + u * 8) =
                    *(const intx4*)&Ts[dvl * 136 + tch + u * 8];
        }
    }
}

// ---------------- out-proj GEMM: 128x64 tile, BK=64, swizzled DMA, relu, bf16 out ----------------
// grid (64, 8): x = m-block (XCD affinity), y = n-block
__global__ __launch_bounds__(256) void gemm_out(
        const short* __restrict__ A, const short* __restrict__ BT,
        const float* __restrict__ bias, short* __restrict__ C) {
    __shared__ __attribute__((aligned(16))) short As[128 * 64];
    __shared__ __attribute__((aligned(16))) short Bs[64 * 64];
    const int tid = threadIdx.x;
    const int w = tid >> 6, ln = tid & 63;
    const int quad = ln >> 4, col = ln & 15;
    const int m0 = blockIdx.x * 128;
    const int n0 = blockIdx.y * 64;
    const int wr = w >> 1, wc = w & 1;

    floatx4 acc[4][2];
#pragma unroll
    for (int i = 0; i < 4; i++)
#pragma unroll
        for (int j = 0; j < 2; j++) acc[i][j] = (floatx4)0.0f;

    for (int k0 = 0; k0 < 512; k0 += 64) {
        __syncthreads();
#pragma unroll
        for (int i = 0; i < 4; i++) {
            const int slot = i * 256 + tid;
            const int r = slot >> 3;
            const int c = (slot & 7) ^ (r & 7);
            gld_lds16(A + (size_t)(m0 + r) * 512 + k0 + c * 8, As + slot * 8);
        }
#pragma unroll
        for (int i = 0; i < 2; i++) {
            const int slot = i * 256 + tid;          // 512 chunks (64 rows)
            const int r = slot >> 3;
            const int c = (slot & 7) ^ (r & 7);
            gld_lds16(BT + (size_t)(n0 + r) * 512 + k0 + c * 8, Bs + slot * 8);
        }
        __syncthreads();
#pragma unroll
        for (int s = 0; s < 2; s++) {
            short8 af[4], bfr[2];
#pragma unroll
            for (int i = 0; i < 4; i++) {
                const int row = wr * 64 + i * 16 + col;
                const int cs = (s * 4 + quad) ^ (col & 7);
                af[i] = *(const short8*)&As[row * 64 + cs * 8];
            }
#pragma unroll
            for (int j = 0; j < 2; j++) {
                const int row = wc * 32 + j * 16 + col;
                const int cs = (s * 4 + quad) ^ (col & 7);
                bfr[j] = *(const short8*)&Bs[row * 64 + cs * 8];
            }
#pragma unroll
            for (int i = 0; i < 4; i++)
#pragma unroll
                for (int j = 0; j < 2; j++)
                    acc[i][j] = mfma16(af[i], bfr[j], acc[i][j]);
        }
    }

#pragma unroll
    for (int j = 0; j < 2; j++) {
        const int cc = n0 + wc * 32 + j * 16 + col;
        const float bj = bias[cc];
#pragma unroll
        for (int i = 0; i < 4; i++)
#pragma unroll
            for (int r = 0; r < 4; r++) {
                const int row = m0 + wr * 64 + i * 16 + quad * 4 + r;
                C[(size_t)row * 512 + cc] = f2bf(fmaxf(acc[i][j][r] + bj, 0.0f));
            }
    }
}

// ---------------- fused flash attention + residual (R9 structure) ----------------
// 512 thr (8 waves), q-tile 128, KT=128, double-buffered DMA staging with
// source-side XOR swizzle; XCD pin h = gid&7.
__global__ __launch_bounds__(512) void attn_kernel(
        const short* __restrict__ Qp, const short* __restrict__ Kp,
        const short* __restrict__ Vt, short* __restrict__ Xo) {
    __shared__ __attribute__((aligned(16))) short Ks[2][128 * 64];
    __shared__ __attribute__((aligned(16))) short Vs[2][64 * 128];
    const int tid = threadIdx.x;
    const int w = tid >> 6, ln = tid & 63;
    const int quad = ln >> 4, col = ln & 15;
    const int gid = blockIdx.x;
    const int h = gid & 7;                  // XCD pin: one head per XCD
    const int rest = gid >> 3;              // 0..63
    const int b = rest >> 3;                // 0..7
    const int qt = rest & 7;                // 0..7
    const int q0 = qt * 128 + w * 16;
    const size_t baseQ = (size_t)b * NSEQ * DIM + (size_t)h * HD;
    const size_t baseV = (size_t)h * HD * NTOK + (size_t)b * NSEQ;
    const float sc = 1.44269504089f / 22.6274169979f;   // log2e / sqrt(512)

    const int ks0 = tid, ks1 = 512 + tid;
    const int kr0 = ks0 >> 3, kc0 = (ks0 & 7) ^ (kr0 & 7);
    const int kr1 = ks1 >> 3, kc1 = (ks1 & 7) ^ (kr1 & 7);
    const int vr0 = ks0 >> 4, vc0 = (ks0 & 15) ^ (vr0 & 15);
    const int vr1 = ks1 >> 4, vc1 = (ks1 & 15) ^ (vr1 & 15);
    const short* kp0 = Kp + baseQ + (size_t)kr0 * DIM + kc0 * 8;
    const short* kp1 = Kp + baseQ + (size_t)kr1 * DIM + kc1 * 8;
    const short* vp0 = Vt + baseV + (size_t)vr0 * NTOK + vc0 * 8;
    const short* vp1 = Vt + baseV + (size_t)vr1 * NTOK + vc1 * 8;
    const int ldsl0 = (w * 64) * 8;
    const int ldsl1 = (512 + w * 64) * 8;

    short8 qa[2];
#pragma unroll
    for (int s = 0; s < 2; s++) {
        short8 raw = *(const short8*)(Qp + baseQ + (size_t)(q0 + col) * DIM + s * 32 + quad * 8);
        short8 sq;
#pragma unroll
        for (int j = 0; j < 8; j++) sq[j] = f2bf(bf2f(raw[j]) * sc);
        qa[s] = sq;
    }

    floatx4 oacc[4];
#pragma unroll
    for (int dt = 0; dt < 4; dt++) oacc[dt] = (floatx4)0.0f;
    float lp = 0.0f;

    gld_lds16(kp0, &Ks[0][ldsl0]);
    gld_lds16(kp1, &Ks[0][ldsl1]);
    gld_lds16(vp0, &Vs[0][ldsl0]);
    gld_lds16(vp1, &Vs[0][ldsl1]);
    __syncthreads();

    for (int t = 0; t < 8; t++) {
        const int cur = t & 1;
        if (t < 7) {
            const int kn = (t + 1) * 128;    // K advances by rows, V by cols
            const int nxt = cur ^ 1;
            gld_lds16(kp0 + (size_t)kn * DIM, &Ks[nxt][ldsl0]);
            gld_lds16(kp1 + (size_t)kn * DIM, &Ks[nxt][ldsl1]);
            gld_lds16(vp0 + kn, &Vs[nxt][ldsl0]);
            gld_lds16(vp1 + kn, &Vs[nxt][ldsl1]);
        }
        const short* Kc = Ks[cur];
        const short* Vc = Vs[cur];
#pragma unroll
        for (int nt = 0; nt < 8; nt++) {
            floatx4 z = (floatx4)0.0f;
#pragma unroll
            for (int s = 0; s < 2; s++) {
                const int cs = (s * 4 + quad) ^ (col & 7);
                const short8 kf = *(const short8*)&Kc[(nt * 16 + col) * 64 + cs * 8];
                z = mfma16(kf, qa[s], z);           // S^T tile
            }
            const float p0 = exp2f(z[0]), p1 = exp2f(z[1]);
            const float p2 = exp2f(z[2]), p3 = exp2f(z[3]);
            lp += (p0 + p1) + (p2 + p3);
            intx2 pd; pd.x = (int)pkbf(p1, p0); pd.y = (int)pkbf(p3, p2);
            const short4v pf = __builtin_bit_cast(short4v, pd);
#pragma unroll
            for (int dt = 0; dt < 4; dt++) {
                const int cs = (nt * 2 + (quad >> 1)) ^ col;
                const short4v vf = *(const short4v*)&Vc[(dt * 16 + col) * 128 + cs * 8 + (quad & 1) * 4];
                oacc[dt] = mfma_pv(pf, vf, oacc[dt]);
            }
        }
        __syncthreads();
    }

    lp += __shfl_xor(lp, 16);
    lp += __shfl_xor(lp, 32);
    float linv[4];
#pragma unroll
    for (int r = 0; r < 4; r++) linv[r] = 1.0f / __shfl(lp, quad * 4 + r);

#pragma unroll
    for (int dt = 0; dt < 4; dt++) {
#pragma unroll
        for (int r = 0; r < 4; r++) {
            const int q = q0 + quad * 4 + r;
            const size_t off = baseQ + (size_t)q * DIM + dt * 16 + col;
            Xo[off] = f2bf(oacc[dt][r] * linv[r] + bf2f(Qp[off]));
        }
    }
}

// ---------------- LayerNorm (wave per row), bf16 in, bf16 out ----------------
__global__ __launch_bounds__(256) void ln_kernel(
        const short* __restrict__ X, const float* __restrict__ g,
        const float* __restrict__ be, short* __restrict__ Yb) {
    const int row = blockIdx.x * 4 + (threadIdx.x >> 6);
    const int ln = threadIdx.x & 63;
    union { intx4 v; short s[8]; } u;
    u.v = *(const intx4*)(X + (size_t)row * DIM + ln * 8);
    float x[8];
#pragma unroll
    for (int j = 0; j < 8; j++) x[j] = bf2f(u.s[j]);
    float s = 0.f, q = 0.f;
#pragma unroll
    for (int j = 0; j < 8; j++) { s += x[j]; q += x[j] * x[j]; }
#pragma unroll
    for (int off = 1; off < 64; off <<= 1) {
        s += __shfl_xor(s, off);
        q += __shfl_xor(q, off);
    }
    const float mean = s * (1.0f / DIM);
    const float var = q * (1.0f / DIM) - mean * mean;
    const float rstd = rsqrtf(var + 1e-5f);
    const int c0 = ln * 8;
    union { intx4 v; short s[8]; } o;
#pragma unroll
    for (int j = 0; j < 8; j++)
        o.s[j] = f2bf((x[j] - mean) * rstd * g[c0 + j] + be[c0 + j]);
    *(intx4*)(Yb + (size_t)row * DIM + c0) = o.v;
}

// ---------------- final: out = LN1(Xln0 + Yrelu), bf16 ins, fp32 out ----------------
__global__ __launch_bounds__(256) void final_kernel(
        const short* __restrict__ Xr, const short* __restrict__ Yr,
        const float* __restrict__ g, const float* __restrict__ be,
        float* __restrict__ out) {
    const int row = blockIdx.x * 4 + (threadIdx.x >> 6);
    const int ln = threadIdx.x & 63;
    const size_t rb = (size_t)row * DIM;
    const int c0 = ln * 8;
    union { intx4 v; short s[8]; } ux, uy;
    ux.v = *(const intx4*)(Xr + rb + c0);
    uy.v = *(const intx4*)(Yr + rb + c0);
    float x[8];
#pragma unroll
    for (int j = 0; j < 8; j++) x[j] = bf2f(ux.s[j]) + bf2f(uy.s[j]);
    float s = 0.f, q = 0.f;
#pragma unroll
    for (int j = 0; j < 8; j++) { s += x[j]; q += x[j] * x[j]; }
#pragma unroll
    for (int off = 1; off < 64; off <<= 1) {
        s += __shfl_xor(s, off);
        q += __shfl_xor(q, off);
    }
    const float mean = s * (1.0f / DIM);
    const float var = q * (1.0f / DIM) - mean * mean;
    const float rstd = rsqrtf(var + 1e-5f);
    float4 f0, f1;
    f0.x = (x[0] - mean) * rstd * g[c0 + 0] + be[c0 + 0];
    f0.y = (x[1] - mean) * rstd * g[c0 + 1] + be[c0 + 1];
    f0.z = (x[2] - mean) * rstd * g[c0 + 2] + be[c0 + 2];
    f0.w = (x[3] - mean) * rstd * g[c0 + 3] + be[c0 + 3];
    f1.x = (x[4] - mean) * rstd * g[c0 + 4] + be[c0 + 4];
    f1.y = (x[5] - mean) * rstd * g[c0 + 5] + be[c0 + 5];
    f1.z = (x[6] - mean) * rstd * g[c0 + 6] + be[c0 + 6];
    f1.w = (x[7] - mean) * rstd * g[c0 + 7] + be[c0 + 7];
    *(float4*)(out + rb + c0)     = f0;
    *(float4*)(out + rb + c0 + 4) = f1;
}

extern "C" void kernel_launch(void* const* d_in, const int* in_sizes, int n_in,
                              void* d_out, int out_size, void* d_ws, size_t ws_size,
                              hipStream_t stream) {
    const float* Q  = (const float*)d_in[0];
    const float* K  = (const float*)d_in[1];
    const float* Wq = (const float*)d_in[2];
    const float* bq = (const float*)d_in[3];
    const float* Wk = (const float*)d_in[4];
    const float* bk = (const float*)d_in[5];
    const float* Wv = (const float*)d_in[6];
    const float* bv = (const float*)d_in[7];
    const float* Wo = (const float*)d_in[8];
    const float* bo = (const float*)d_in[9];
    const float* g0 = (const float*)d_in[10];
    const float* b0 = (const float*)d_in[11];
    const float* g1 = (const float*)d_in[12];
    const float* b1 = (const float*)d_in[13];
    float* out = (float*)d_out;

    const size_t NE = (size_t)NTOK * DIM;
    char* p = (char*)d_ws;
    short* WqT  = (short*)p; p += 512 * 512 * 2;
    short* WkT  = (short*)p; p += 512 * 512 * 2;
    short* WvT  = (short*)p; p += 512 * 512 * 2;
    short* WoT  = (short*)p; p += 512 * 512 * 2;
    short* Qpb  = (short*)p; p += NE * 2;
    short* Kpb  = (short*)p; p += NE * 2;
    short* Vt   = (short*)p; p += NE * 2;   // [dv=512][tok=8192]
    short* Xat  = (short*)p; p += NE * 2;   // attn out + residual, bf16
    short* Xl0b = (short*)p; p += NE * 2;   // LN0 out, bf16
    short* Yob  = (short*)p; p += NE * 2;   // relu(out-proj), bf16

    prep_kernel<<<256, 256, 0, stream>>>(Wq, Wk, Wv, Wo, WqT, WkT, WvT, WoT);
    proj_kernel<<<dim3(64, 12), 256, 0, stream>>>(Q, K, WqT, WkT, WvT,
                                                  bq, bk, bv, Qpb, Kpb, Vt);
    attn_kernel<<<512, 512, 0, stream>>>(Qpb, Kpb, Vt, Xat);
    ln_kernel<<<2048, 256, 0, stream>>>(Xat, g0, b0, Xl0b);
    gemm_out<<<dim3(64, 8), 256, 0, stream>>>(Xl0b, WoT, bo, Yob);
    final_kernel<<<2048, 256, 0, stream>>>(Xl0b, Yob, g1, b1, out);
}